// Round 14
// baseline (5994.184 us; speedup 1.0000x reference)
//
#include <hip/hip_runtime.h>
#include <math.h>

#define B_  4
#define L_  512
#define D_  512
#define DIN 1024
#define DST 16
#define DCV 4
#define DTR 32
#define NL  3
#define H2  256

typedef _Float16 __f16;
typedef __f16 f16x2 __attribute__((ext_vector_type(2)));
typedef __f16 half8 __attribute__((ext_vector_type(8)));
typedef float f32x4v __attribute__((ext_vector_type(4)));
typedef unsigned uint4v __attribute__((ext_vector_type(4)));

__device__ __forceinline__ float fast_sigmoid(float x) { return 1.f / (1.f + __expf(-x)); }
__device__ __forceinline__ float fast_tanh(float x) { return 2.f / (1.f + __expf(-2.f * x)) - 1.f; }

__device__ __forceinline__ float dot2f(unsigned a, unsigned b, float c) {
  return __builtin_amdgcn_fdot2(__builtin_bit_cast(f16x2, a),
                                __builtin_bit_cast(f16x2, b), c, false);
}
__device__ __forceinline__ unsigned packf16(float a, float b) {
  f16x2 p; p.x = (__f16)a; p.y = (__f16)b;
  return __builtin_bit_cast(unsigned, p);
}

// ---------------- f16 MFMA GEMM: C[M,N] = A[M,K] @ W[N,K]^T (+bias +bias2) ----------------
template<bool ACC>
__global__ __launch_bounds__(256) void gemm_mfma(
    const float* __restrict__ A, const float* __restrict__ W, float* __restrict__ C,
    int M, int N, int K, int lda, int ldb, int ldc,
    const float* __restrict__ bias, const float* __restrict__ bias2)
{
  __shared__ uint4v As[1024];   // [row][8 kb-slots], phys slot = kb ^ (row&7), 16KB
  __shared__ uint4v Bs[1024];   // 16KB
  const int tid  = threadIdx.x;
  const int lane = tid & 63, wid = tid >> 6;
  const int wr = wid >> 1, wc = wid & 1;
  const int fr = lane & 15, fq = lane >> 4;
  const int m0 = blockIdx.y * 128, n0 = blockIdx.x * 128;
  const int srow = tid >> 3, skb = tid & 7;

  f32x4v acc[4][4] = {};
  for (int k0 = 0; k0 < K; k0 += 64) {
    const float* Abase = A + (size_t)m0 * lda + k0;
    const float* Bbase = W + (size_t)n0 * ldb + k0;
    #pragma unroll
    for (int i = 0; i < 4; ++i) {
      int row = srow + i * 32;
      const float4* pa = (const float4*)(Abase + (size_t)row * lda + skb * 8);
      const float4* pb = (const float4*)(Bbase + (size_t)row * ldb + skb * 8);
      float4 a0 = pa[0], a1 = pa[1];
      float4 b0 = pb[0], b1 = pb[1];
      uint4v ap, bp;
      ap.x = packf16(a0.x, a0.y); ap.y = packf16(a0.z, a0.w);
      ap.z = packf16(a1.x, a1.y); ap.w = packf16(a1.z, a1.w);
      bp.x = packf16(b0.x, b0.y); bp.y = packf16(b0.z, b0.w);
      bp.z = packf16(b1.x, b1.y); bp.w = packf16(b1.z, b1.w);
      As[row * 8 + (skb ^ (row & 7))] = ap;
      Bs[row * 8 + (skb ^ (row & 7))] = bp;
    }
    __syncthreads();
    #pragma unroll
    for (int ks = 0; ks < 2; ++ks) {
      half8 af[4], bf[4];
      #pragma unroll
      for (int mt = 0; mt < 4; ++mt) {
        int row = wr * 64 + mt * 16 + fr;
        int kb = ks * 4 + fq;
        af[mt] = __builtin_bit_cast(half8, As[row * 8 + (kb ^ (row & 7))]);
      }
      #pragma unroll
      for (int nt = 0; nt < 4; ++nt) {
        int row = wc * 64 + nt * 16 + fr;
        int kb = ks * 4 + fq;
        bf[nt] = __builtin_bit_cast(half8, Bs[row * 8 + (kb ^ (row & 7))]);
      }
      #pragma unroll
      for (int mt = 0; mt < 4; ++mt)
        #pragma unroll
        for (int nt = 0; nt < 4; ++nt)
          acc[mt][nt] = __builtin_amdgcn_mfma_f32_16x16x32_f16(af[mt], bf[nt], acc[mt][nt], 0, 0, 0);
    }
    __syncthreads();
  }
  #pragma unroll
  for (int nt = 0; nt < 4; ++nt) {
    int n = n0 + wc * 64 + nt * 16 + fr;
    float bv = (bias ? bias[n] : 0.f) + (bias2 ? bias2[n] : 0.f);
    #pragma unroll
    for (int mt = 0; mt < 4; ++mt) {
      #pragma unroll
      for (int r = 0; r < 4; ++r) {
        int m = m0 + wr * 64 + mt * 16 + fq * 4 + r;
        float v = acc[mt][nt][r] + bv;
        if (ACC) C[(size_t)m * ldc + n] += v; else C[(size_t)m * ldc + n] = v;
      }
    }
  }
}

// ---------------- fp32 fallback GEMM (small/odd shapes) ----------------
template<int ACT>
__global__ __launch_bounds__(256) void gemm_nt(
    const float* __restrict__ A, const float* __restrict__ Bm, float* __restrict__ C,
    int M, int N, int K, int lda, int ldb, int ldc,
    const float* __restrict__ bias)
{
  __shared__ __align__(16) float As[16][64];
  __shared__ __align__(16) float Bs[16][64];
  const int tid = threadIdx.x;
  const int tx = tid & 15, ty = tid >> 4;
  const int m0 = blockIdx.y * 64, n0 = blockIdx.x * 64;
  const int r = tid >> 2, kq = (tid & 3) * 4;
  float acc[4][4] = {};
  for (int k0 = 0; k0 < K; k0 += 16) {
    float4 av = *(const float4*)(A  + (size_t)(m0 + r) * lda + (k0 + kq));
    float4 bv = *(const float4*)(Bm + (size_t)(n0 + r) * ldb + (k0 + kq));
    As[kq+0][r] = av.x; As[kq+1][r] = av.y; As[kq+2][r] = av.z; As[kq+3][r] = av.w;
    Bs[kq+0][r] = bv.x; Bs[kq+1][r] = bv.y; Bs[kq+2][r] = bv.z; Bs[kq+3][r] = bv.w;
    __syncthreads();
    #pragma unroll
    for (int kk = 0; kk < 16; ++kk) {
      float4 a = *(const float4*)(&As[kk][ty*4]);
      float4 b = *(const float4*)(&Bs[kk][tx*4]);
      float aa[4] = {a.x, a.y, a.z, a.w};
      float bb[4] = {b.x, b.y, b.z, b.w};
      #pragma unroll
      for (int i = 0; i < 4; ++i)
        #pragma unroll
        for (int j = 0; j < 4; ++j)
          acc[i][j] = fmaf(aa[i], bb[j], acc[i][j]);
    }
    __syncthreads();
  }
  #pragma unroll
  for (int i = 0; i < 4; ++i) {
    int m = m0 + ty*4 + i;
    float* cp = C + (size_t)m * ldc + n0 + tx*4;
    #pragma unroll
    for (int j = 0; j < 4; ++j) {
      int n = n0 + tx*4 + j;
      float v = acc[i][j];
      if (bias)  v += bias[n];
      if (ACT == 1) v = (v > 20.f) ? v : log1pf(__expf(v));
      cp[j] = v;
    }
  }
}

// xpw_pad[r][k] = r<64 ? xpw[r][k] : 0   (128x1024)
__global__ __launch_bounds__(256) void pad_xpw(
    const float* __restrict__ src, float* __restrict__ dst)
{
  int t = blockIdx.x * 256 + threadIdx.x;
  int r = t >> 10;
  dst[t] = (r < 64) ? src[t] : 0.f;
}

// pack whh f32 -> f16 uint4 for the split-LSTM:
// dst idx decode: u4sel=idx&1; lane=(idx>>1)&63; w=(idx>>7)&7; g=(idx>>10)&3;
// ug=(idx>>12)&7; dir=idx>>15.  unit j = ug*32 + w*4 + (lane>>4); ks = lane&15;
// kbase = ks*16 + u4sel*8. Covers whh[dir][g*256+j][kbase..+8).
__global__ __launch_bounds__(256) void pack_whh(
    const float* __restrict__ whh, uint4* __restrict__ wpk)
{
  int idx = blockIdx.x * 256 + threadIdx.x;   // [0, 65536)
  int u4sel = idx & 1;
  int lane  = (idx >> 1) & 63;
  int w     = (idx >> 7) & 7;
  int g     = (idx >> 10) & 3;
  int ug    = (idx >> 12) & 7;
  int dir   = idx >> 15;
  int j  = ug * 32 + w * 4 + (lane >> 4);
  int ks = lane & 15;
  const float* src = whh + (size_t)dir * 262144 + (size_t)(g * 256 + j) * 256 + ks * 16 + u4sel * 8;
  float4 fa = ((const float4*)src)[0];
  float4 fb = ((const float4*)src)[1];
  uint4 pk;
  pk.x = packf16(fa.x, fa.y); pk.y = packf16(fa.z, fa.w);
  pk.z = packf16(fb.x, fb.y); pk.w = packf16(fb.z, fb.w);
  wpk[idx] = pk;
}

// u[b,l,c] = silu(cb[c] + sum_k xin[b,l-3+k,c] * cw[c,k])
__global__ __launch_bounds__(256) void conv_silu(
    const float* __restrict__ xz, const float* __restrict__ cw, const float* __restrict__ cb,
    float* __restrict__ u)
{
  int t = blockIdx.x * 256 + threadIdx.x;
  int c  = t & (DIN - 1);
  int bl = t >> 10;
  int l  = bl & (L_ - 1);
  float acc = cb[c];
  #pragma unroll
  for (int k = 0; k < DCV; ++k) {
    int ls = l + k - (DCV - 1);
    if (ls >= 0)
      acc = fmaf(xz[(size_t)(bl + k - (DCV - 1)) * 2048 + c], cw[c * DCV + k], acc);
  }
  u[t] = acc * fast_sigmoid(acc);
}

// selective scan: thread per (b,c,n). 4-deep rotating software prefetch.
__global__ __launch_bounds__(256) void scan_kernel(
    const float* __restrict__ dt, const float* __restrict__ u,
    const float* __restrict__ xdbl, const float* __restrict__ xz,
    const float* __restrict__ A_log, const float* __restrict__ Dp,
    float* __restrict__ y)
{
  int t = blockIdx.x * 256 + threadIdx.x;
  int n  = t & 15;
  int bc = t >> 4;
  int c  = bc & (DIN - 1);
  int b  = bc >> 10;
  float Ac = -__expf(A_log[c * DST + n]);
  float Dc = Dp[c];
  float h = 0.f;
  const size_t row = (size_t)b * L_;

#define DECLP(i) float dtv##i, uv##i, Bn##i, Cn##i, zv##i;
  DECLP(0) DECLP(1) DECLP(2) DECLP(3)
#define LOADP(i, l) { \
    const size_t nb_ = row + (l); \
    dtv##i = dt[nb_ * DIN + c]; \
    uv##i  = u [nb_ * DIN + c]; \
    Bn##i  = xdbl[nb_ * 128 + 32 + n]; \
    Cn##i  = xdbl[nb_ * 128 + 48 + n]; \
    zv##i  = xz[nb_ * 2048 + 1024 + c]; }
#define STEPP(i, l) { \
    float dA_ = __expf(dtv##i * Ac); \
    h = fmaf(dA_, h, (dtv##i * uv##i) * Bn##i); \
    float p_ = h * Cn##i; \
    p_ += __shfl_xor(p_, 1, 64); \
    p_ += __shfl_xor(p_, 2, 64); \
    p_ += __shfl_xor(p_, 4, 64); \
    p_ += __shfl_xor(p_, 8, 64); \
    if (n == 0) { \
      float yv_ = p_ + uv##i * Dc; \
      yv_ *= zv##i * fast_sigmoid(zv##i); \
      y[(row + (l)) * DIN + c] = yv_; \
    } }

  LOADP(0, 0) LOADP(1, 1) LOADP(2, 2) LOADP(3, 3)
  for (int l = 0; l < L_ - 4; l += 4) {
    STEPP(0, l)     LOADP(0, l + 4)
    STEPP(1, l + 1) LOADP(1, l + 5)
    STEPP(2, l + 2) LOADP(2, l + 6)
    STEPP(3, l + 3) LOADP(3, l + 7)
  }
  STEPP(0, L_ - 4) STEPP(1, L_ - 3) STEPP(2, L_ - 2) STEPP(3, L_ - 1)
#undef DECLP
#undef LOADP
#undef STEPP
}

// out[row*ldo + c] = layernorm(a[row] + mo[row]) * g + b
__global__ __launch_bounds__(64) void resid_ln(
    const float* __restrict__ a, const float* __restrict__ mo,
    const float* __restrict__ g, const float* __restrict__ bta,
    float* __restrict__ outm, int ldo)
{
  int row = blockIdx.x;
  int lane = threadIdx.x;
  const float* pa = a  + (size_t)row * 512;
  const float* pb = mo + (size_t)row * 512;
  float v[8];
  float s = 0.f, s2 = 0.f;
  #pragma unroll
  for (int i = 0; i < 8; ++i) {
    float x = pa[lane + i * 64] + pb[lane + i * 64];
    v[i] = x; s += x; s2 += x * x;
  }
  #pragma unroll
  for (int off = 1; off < 64; off <<= 1) {
    s  += __shfl_xor(s,  off, 64);
    s2 += __shfl_xor(s2, off, 64);
  }
  float mean = s * (1.f / 512.f);
  float var  = s2 * (1.f / 512.f) - mean * mean;
  float rstd = rsqrtf(var + 1e-5f);
  #pragma unroll
  for (int i = 0; i < 8; ++i) {
    int cidx = lane + i * 64;
    outm[(size_t)row * ldo + cidx] = (v[i] - mean) * rstd * g[cidx] + bta[cidx];
  }
}

// ---------------- split LSTM recurrence ----------------
// 16 blocks = 2 dirs x 8 unit-groups (32 units). 512 thr = (unit jl = t>>4) x
// (k-slice ks = t&15, 16 k each). Batch-shared: each thread's 4-gate weight
// slice (8 named uint4 = 32 VGPRs -- small enough to stay register-resident)
// dots against ALL 4 batches' h. h exchanged via rotating per-step global
// buffer with agent-scope atomics (cross-XCD + graph-replay safe); 8-block
// per-dir spin barrier on per-step counters (memset to 0 each call).

#define HDECL(b) unsigned h##b##0,h##b##1,h##b##2,h##b##3,h##b##4,h##b##5,h##b##6,h##b##7;
#define HLOAD(b) { const unsigned* hp_ = hrow + (b)*128; \
  h##b##0 = __hip_atomic_load(hp_+0, __ATOMIC_RELAXED, __HIP_MEMORY_SCOPE_AGENT); \
  h##b##1 = __hip_atomic_load(hp_+1, __ATOMIC_RELAXED, __HIP_MEMORY_SCOPE_AGENT); \
  h##b##2 = __hip_atomic_load(hp_+2, __ATOMIC_RELAXED, __HIP_MEMORY_SCOPE_AGENT); \
  h##b##3 = __hip_atomic_load(hp_+3, __ATOMIC_RELAXED, __HIP_MEMORY_SCOPE_AGENT); \
  h##b##4 = __hip_atomic_load(hp_+4, __ATOMIC_RELAXED, __HIP_MEMORY_SCOPE_AGENT); \
  h##b##5 = __hip_atomic_load(hp_+5, __ATOMIC_RELAXED, __HIP_MEMORY_SCOPE_AGENT); \
  h##b##6 = __hip_atomic_load(hp_+6, __ATOMIC_RELAXED, __HIP_MEMORY_SCOPE_AGENT); \
  h##b##7 = __hip_atomic_load(hp_+7, __ATOMIC_RELAXED, __HIP_MEMORY_SCOPE_AGENT); }
#define DOTG(g, Wa, Wb, b) \
  a##g##b = dot2f(Wa.x, h##b##0, a##g##b); a##g##b = dot2f(Wa.y, h##b##1, a##g##b); \
  a##g##b = dot2f(Wa.z, h##b##2, a##g##b); a##g##b = dot2f(Wa.w, h##b##3, a##g##b); \
  a##g##b = dot2f(Wb.x, h##b##4, a##g##b); a##g##b = dot2f(Wb.y, h##b##5, a##g##b); \
  a##g##b = dot2f(Wb.z, h##b##6, a##g##b); a##g##b = dot2f(Wb.w, h##b##7, a##g##b);
#define DOTB(b) DOTG(0,W0a,W0b,b) DOTG(1,W1a,W1b,b) DOTG(2,W2a,W2b,b) DOTG(3,W3a,W3b,b)
#define RED(a) a += __shfl_xor(a,1,64); a += __shfl_xor(a,2,64); \
               a += __shfl_xor(a,4,64); a += __shfl_xor(a,8,64);
#define PTW(b) { \
    float si_ = fast_sigmoid(a0##b); \
    float sf_ = fast_sigmoid(a1##b); \
    float tg_ = fast_tanh(a2##b); \
    float so_ = fast_sigmoid(a3##b); \
    c##b = fmaf(sf_, c##b, si_ * tg_); \
    hv##b = so_ * fast_tanh(c##b); }

__global__ __launch_bounds__(512, 1) void lstm_rec(
    const float* __restrict__ gx, const uint4* __restrict__ wpk,
    float* __restrict__ comb, unsigned* __restrict__ hst, unsigned* __restrict__ cnt)
{
  const int bid = blockIdx.x;
  const int dir = bid >> 3, ug = bid & 7;
  const int t = threadIdx.x;
  const int jl = t >> 4, ks = t & 15;
  const int j  = ug * 32 + jl;

  // register-resident weights: 4 gates x 32B k-slice
  const uint4* wsl = wpk + ((size_t)(dir * 8 + ug) * 4096);
  const int wi_ = (t >> 6) * 128 + (t & 63) * 2;
  uint4 W0a = wsl[0*1024 + wi_], W0b = wsl[0*1024 + wi_ + 1];
  uint4 W1a = wsl[1*1024 + wi_], W1b = wsl[1*1024 + wi_ + 1];
  uint4 W2a = wsl[2*1024 + wi_], W2b = wsl[2*1024 + wi_ + 1];
  uint4 W3a = wsl[3*1024 + wi_], W3b = wsl[3*1024 + wi_ + 1];

  const int g0 = ks & 3, b0 = ks >> 2;    // this lane's gx assignment
  float c0 = 0.f, c1 = 0.f, c2 = 0.f, c3 = 0.f;
  const float* gxb = gx + dir * 1024 + g0 * 256 + j;
  float* combp = comb + 512 + dir * 256 + j;
  unsigned* hdir = hst + (size_t)dir * 512 * 512;   // [s][b][128] dwords
  unsigned* cdir = cnt + dir * 512;

  int l = dir ? (L_ - 1) : 0;
  const int lstep = dir ? -1 : 1;
  float gxv = gxb[(size_t)(b0 * 512 + l) * 2048];

  for (int s = 0; s < L_; ++s) {
    float gxn = 0.f;
    if (s + 1 < L_) gxn = gxb[(size_t)(b0 * 512 + l + lstep) * 2048];

    float a00=0,a01=0,a02=0,a03=0, a10=0,a11=0,a12=0,a13=0,
          a20=0,a21=0,a22=0,a23=0, a30=0,a31=0,a32=0,a33=0;
    if (s > 0) {
      const unsigned* hrow = hdir + (size_t)(s - 1) * 512 + ks * 8;
      HDECL(0) HDECL(1) HDECL(2) HDECL(3)
      HLOAD(0) HLOAD(1) HLOAD(2) HLOAD(3)
      DOTB(0) DOTB(1) DOTB(2) DOTB(3)
    }
    // inject gx once (lane ks == b*4+g)
    a00 += (ks== 0)?gxv:0.f; a10 += (ks== 1)?gxv:0.f; a20 += (ks== 2)?gxv:0.f; a30 += (ks== 3)?gxv:0.f;
    a01 += (ks== 4)?gxv:0.f; a11 += (ks== 5)?gxv:0.f; a21 += (ks== 6)?gxv:0.f; a31 += (ks== 7)?gxv:0.f;
    a02 += (ks== 8)?gxv:0.f; a12 += (ks== 9)?gxv:0.f; a22 += (ks==10)?gxv:0.f; a32 += (ks==11)?gxv:0.f;
    a03 += (ks==12)?gxv:0.f; a13 += (ks==13)?gxv:0.f; a23 += (ks==14)?gxv:0.f; a33 += (ks==15)?gxv:0.f;
    // butterfly sum over the 16 ks lanes (all lanes get totals)
    RED(a00) RED(a01) RED(a02) RED(a03)
    RED(a10) RED(a11) RED(a12) RED(a13)
    RED(a20) RED(a21) RED(a22) RED(a23)
    RED(a30) RED(a31) RED(a32) RED(a33)

    float hv0, hv1, hv2, hv3;
    PTW(0) PTW(1) PTW(2) PTW(3)

    if (ks == 0) {
      combp[(size_t)(0 * 512 + l) * 1024] = hv0;
      combp[(size_t)(1 * 512 + l) * 1024] = hv1;
      combp[(size_t)(2 * 512 + l) * 1024] = hv2;
      combp[(size_t)(3 * 512 + l) * 1024] = hv3;
    }
    // pack (h[j], h[j+1]) and publish
    float hp0 = __shfl_xor(hv0, 16, 64);
    float hp1 = __shfl_xor(hv1, 16, 64);
    float hp2 = __shfl_xor(hv2, 16, 64);
    float hp3 = __shfl_xor(hv3, 16, 64);
    if (ks == 0 && !(jl & 1)) {
      unsigned* hw = hdir + (size_t)s * 512 + (j >> 1);
      __hip_atomic_store(hw + 0*128, packf16(hv0, hp0), __ATOMIC_RELAXED, __HIP_MEMORY_SCOPE_AGENT);
      __hip_atomic_store(hw + 1*128, packf16(hv1, hp1), __ATOMIC_RELAXED, __HIP_MEMORY_SCOPE_AGENT);
      __hip_atomic_store(hw + 2*128, packf16(hv2, hp2), __ATOMIC_RELAXED, __HIP_MEMORY_SCOPE_AGENT);
      __hip_atomic_store(hw + 3*128, packf16(hv3, hp3), __ATOMIC_RELAXED, __HIP_MEMORY_SCOPE_AGENT);
    }
    if (s + 1 < L_) {
      __threadfence();
      __syncthreads();
      if (t == 0) {
        atomicAdd(&cdir[s], 1u);
        while (__hip_atomic_load(&cdir[s], __ATOMIC_ACQUIRE, __HIP_MEMORY_SCOPE_AGENT) < 8u) {}
      }
      __syncthreads();
    }
    gxv = gxn;
    l += lstep;
  }
}

extern "C" void kernel_launch(void* const* d_in, const int* in_sizes, int n_in,
                              void* d_out, int out_size, void* d_ws, size_t ws_size,
                              hipStream_t stream)
{
  const float* x    = (const float*)d_in[0];
  const float* wi   = (const float*)d_in[1];
  const float* cw   = (const float*)d_in[2];
  const float* cb   = (const float*)d_in[3];
  const float* xpw  = (const float*)d_in[4];
  const float* dw   = (const float*)d_in[5];
  const float* db   = (const float*)d_in[6];
  const float* Alog = (const float*)d_in[7];
  const float* Dp   = (const float*)d_in[8];
  const float* wo   = (const float*)d_in[9];
  const float* lng  = (const float*)d_in[10];
  const float* lnb  = (const float*)d_in[11];
  const float* wih  = (const float*)d_in[12];
  const float* whh  = (const float*)d_in[13];
  const float* bih  = (const float*)d_in[14];
  const float* bhh  = (const float*)d_in[15];
  const float* fw   = (const float*)d_in[16];
  const float* fb   = (const float*)d_in[17];
  float* out = (float*)d_out;

  float* F    = (float*)d_ws;
  float* xz   = F;                 // 4,194,304 floats; aliased with gx
  float* gx   = F;
  float* u    = F + 4194304;       // 2,097,152
  float* xdbl = F + 6291456;       //   262,144 (2048 x 128, padded)
  float* dt   = F + 6553600;       // 2,097,152
  float* ybuf = F + 8650752;       // 2,097,152
  float* mo   = F + 10747904;      // 1,048,576
  float* mbuf = F + 11796480;      // 1,048,576
  float* comb = F + 12845056;      // 2,097,152  [m | lf | lb], ld 1024
  uint4* wpk  = (uint4*)(F + 14942208);  // 1MB packed whh
  // lstm h-exchange aliases (consumed before the mamba loop rewrites them):
  unsigned* hst = (unsigned*)dt;          // 2 dirs x 512 steps x 512 dwords = 2MB
  unsigned* cnt = (unsigned*)ybuf;        // 1024 dwords of counters
  float* xpw_pad = mo;             // pad consumed before mo is written

  const int M = B_ * L_;           // 2048
  dim3 blk(256);

  gemm_mfma<false><<<dim3(2048/128, M/128), blk, 0, stream>>>(
      x, wih, gx, M, 2048, 512, 512, 512, 2048, bih, bhh);
  pack_whh<<<dim3(256), blk, 0, stream>>>(whh, wpk);
  hipMemsetAsync(cnt, 0, 1024 * sizeof(unsigned), stream);
  lstm_rec<<<dim3(16), dim3(512), 0, stream>>>(gx, wpk, comb, hst, cnt);

  for (int i = 0; i < NL; ++i) {
    const float* min = (i == 0) ? x : mbuf;
    pad_xpw<<<dim3(512), blk, 0, stream>>>(xpw + (size_t)i*64*1024, xpw_pad);
    gemm_mfma<false><<<dim3(2048/128, M/128), blk, 0, stream>>>(
        min, wi + (size_t)i*2048*512, xz, M, 2048, 512, 512, 512, 2048, nullptr, nullptr);
    conv_silu<<<dim3((M*DIN)/256), blk, 0, stream>>>(
        xz, cw + (size_t)i*DIN*DCV, cb + i*DIN, u);
    gemm_mfma<false><<<dim3(1, M/128), blk, 0, stream>>>(
        u, xpw_pad, xdbl, M, 128, 1024, 1024, 1024, 128, nullptr, nullptr);
    gemm_nt<1><<<dim3(1024/64, M/64), blk, 0, stream>>>(
        xdbl, dw + (size_t)i*1024*32, dt, M, 1024, 32, 128, 32, 1024, db + i*1024);
    scan_kernel<<<dim3((B_*DIN*DST)/256), blk, 0, stream>>>(
        dt, u, xdbl, xz, Alog + (size_t)i*DIN*DST, Dp + i*DIN, ybuf);
    gemm_mfma<false><<<dim3(512/128, M/128), blk, 0, stream>>>(
        ybuf, wo + (size_t)i*512*1024, mo, M, 512, 1024, 1024, 1024, 512, nullptr, nullptr);
    if (i < NL - 1)
      resid_ln<<<dim3(M), dim3(64), 0, stream>>>(
          min, mo, lng + i*512, lnb + i*512, mbuf, 512);
    else
      resid_ln<<<dim3(M), dim3(64), 0, stream>>>(
          min, mo, lng + i*512, lnb + i*512, comb, 1024);
  }

  // fusion: out = comb @ fusion_w^T + fb  (single K=1024 MFMA GEMM)
  gemm_mfma<false><<<dim3(512/128, M/128), blk, 0, stream>>>(
      comb, fw, out, M, 512, 1024, 1024, 1024, 512, fb, nullptr);
}

// Round 15
// 1554.186 us; speedup vs baseline: 3.8568x; 3.8568x over previous
//
#include <hip/hip_runtime.h>
#include <math.h>

#define B_  4
#define L_  512
#define D_  512
#define DIN 1024
#define DST 16
#define DCV 4
#define DTR 32
#define NL  3
#define H2  256

typedef _Float16 __f16;
typedef __f16 f16x2 __attribute__((ext_vector_type(2)));
typedef __f16 half8 __attribute__((ext_vector_type(8)));
typedef float f32x4v __attribute__((ext_vector_type(4)));
typedef unsigned uint4v __attribute__((ext_vector_type(4)));

__device__ __forceinline__ float fast_sigmoid(float x) { return 1.f / (1.f + __expf(-x)); }
__device__ __forceinline__ float fast_tanh(float x) { return 2.f / (1.f + __expf(-2.f * x)) - 1.f; }

__device__ __forceinline__ float dot2f(unsigned a, unsigned b, float c) {
  return __builtin_amdgcn_fdot2(__builtin_bit_cast(f16x2, a),
                                __builtin_bit_cast(f16x2, b), c, false);
}
__device__ __forceinline__ unsigned packf16(float a, float b) {
  f16x2 p; p.x = (__f16)a; p.y = (__f16)b;
  return __builtin_bit_cast(unsigned, p);
}

// ---------------- f16-operand MFMA GEMM: C[M,N] = A[M,K] @ W[N,K]^T (+bias +bias2) ----------------
// A, W pre-packed f16. 128x128 tile, BK=64, 4 waves. Staging = pure uint4 loads
// (no pack VALU, half the bytes of the old f32-staging version).
template<bool ACC>
__global__ __launch_bounds__(256) void gemm_mfma_h(
    const __f16* __restrict__ A, const __f16* __restrict__ W, float* __restrict__ C,
    int M, int N, int K, int lda, int ldb, int ldc,
    const float* __restrict__ bias, const float* __restrict__ bias2)
{
  __shared__ uint4v As[1024];   // [row][8 kb-slots], phys slot = kb ^ (row&7)
  __shared__ uint4v Bs[1024];
  const int tid  = threadIdx.x;
  const int lane = tid & 63, wid = tid >> 6;
  const int wr = wid >> 1, wc = wid & 1;
  const int fr = lane & 15, fq = lane >> 4;
  const int m0 = blockIdx.y * 128, n0 = blockIdx.x * 128;
  const int srow = tid >> 3, skb = tid & 7;

  f32x4v acc[4][4] = {};
  for (int k0 = 0; k0 < K; k0 += 64) {
    const __f16* Ab = A + (size_t)m0 * lda + k0;
    const __f16* Bb = W + (size_t)n0 * ldb + k0;
    #pragma unroll
    for (int i = 0; i < 4; ++i) {
      int row = srow + i * 32;
      uint4v ap = *(const uint4v*)(Ab + (size_t)row * lda + skb * 8);
      uint4v bp = *(const uint4v*)(Bb + (size_t)row * ldb + skb * 8);
      As[row * 8 + (skb ^ (row & 7))] = ap;
      Bs[row * 8 + (skb ^ (row & 7))] = bp;
    }
    __syncthreads();
    #pragma unroll
    for (int ks = 0; ks < 2; ++ks) {
      half8 af[4], bf[4];
      #pragma unroll
      for (int mt = 0; mt < 4; ++mt) {
        int row = wr * 64 + mt * 16 + fr;
        int kb = ks * 4 + fq;
        af[mt] = __builtin_bit_cast(half8, As[row * 8 + (kb ^ (row & 7))]);
      }
      #pragma unroll
      for (int nt = 0; nt < 4; ++nt) {
        int row = wc * 64 + nt * 16 + fr;
        int kb = ks * 4 + fq;
        bf[nt] = __builtin_bit_cast(half8, Bs[row * 8 + (kb ^ (row & 7))]);
      }
      #pragma unroll
      for (int mt = 0; mt < 4; ++mt)
        #pragma unroll
        for (int nt = 0; nt < 4; ++nt)
          acc[mt][nt] = __builtin_amdgcn_mfma_f32_16x16x32_f16(af[mt], bf[nt], acc[mt][nt], 0, 0, 0);
    }
    __syncthreads();
  }
  #pragma unroll
  for (int nt = 0; nt < 4; ++nt) {
    int n = n0 + wc * 64 + nt * 16 + fr;
    float bv = (bias ? bias[n] : 0.f) + (bias2 ? bias2[n] : 0.f);
    #pragma unroll
    for (int mt = 0; mt < 4; ++mt) {
      #pragma unroll
      for (int r = 0; r < 4; ++r) {
        int m = m0 + wr * 64 + mt * 16 + fq * 4 + r;
        float v = acc[mt][nt][r] + bv;
        if (ACC) C[(size_t)m * ldc + n] += v; else C[(size_t)m * ldc + n] = v;
      }
    }
  }
}

// ---------------- fp32 fallback GEMM (dt: K=32) ----------------
template<int ACT>
__global__ __launch_bounds__(256) void gemm_nt(
    const float* __restrict__ A, const float* __restrict__ Bm, float* __restrict__ C,
    int M, int N, int K, int lda, int ldb, int ldc,
    const float* __restrict__ bias)
{
  __shared__ __align__(16) float As[16][64];
  __shared__ __align__(16) float Bs[16][64];
  const int tid = threadIdx.x;
  const int tx = tid & 15, ty = tid >> 4;
  const int m0 = blockIdx.y * 64, n0 = blockIdx.x * 64;
  const int r = tid >> 2, kq = (tid & 3) * 4;
  float acc[4][4] = {};
  for (int k0 = 0; k0 < K; k0 += 16) {
    float4 av = *(const float4*)(A  + (size_t)(m0 + r) * lda + (k0 + kq));
    float4 bv = *(const float4*)(Bm + (size_t)(n0 + r) * ldb + (k0 + kq));
    As[kq+0][r] = av.x; As[kq+1][r] = av.y; As[kq+2][r] = av.z; As[kq+3][r] = av.w;
    Bs[kq+0][r] = bv.x; Bs[kq+1][r] = bv.y; Bs[kq+2][r] = bv.z; Bs[kq+3][r] = bv.w;
    __syncthreads();
    #pragma unroll
    for (int kk = 0; kk < 16; ++kk) {
      float4 a = *(const float4*)(&As[kk][ty*4]);
      float4 b = *(const float4*)(&Bs[kk][tx*4]);
      float aa[4] = {a.x, a.y, a.z, a.w};
      float bb[4] = {b.x, b.y, b.z, b.w};
      #pragma unroll
      for (int i = 0; i < 4; ++i)
        #pragma unroll
        for (int j = 0; j < 4; ++j)
          acc[i][j] = fmaf(aa[i], bb[j], acc[i][j]);
    }
    __syncthreads();
  }
  #pragma unroll
  for (int i = 0; i < 4; ++i) {
    int m = m0 + ty*4 + i;
    float* cp = C + (size_t)m * ldc + n0 + tx*4;
    #pragma unroll
    for (int j = 0; j < 4; ++j) {
      int n = n0 + tx*4 + j;
      float v = acc[i][j];
      if (bias)  v += bias[n];
      if (ACT == 1) v = (v > 20.f) ? v : log1pf(__expf(v));
      cp[j] = v;
    }
  }
}

// generic f32 -> f16 pack
__global__ __launch_bounds__(256) void packh(
    const float* __restrict__ src, __f16* __restrict__ dst, int n)
{
  int t = blockIdx.x * 256 + threadIdx.x;
  if (t < n) dst[t] = (__f16)src[t];
}

// all 3 layers' x_proj weights, zero-padded 64->128 rows, packed f16
__global__ __launch_bounds__(256) void pack_xpw_h(
    const float* __restrict__ xpw, __f16* __restrict__ dst)
{
  int t = blockIdx.x * 256 + threadIdx.x;   // [0, 3*131072)
  int layer = t >> 17;
  int r = (t >> 10) & 127;
  int k = t & 1023;
  dst[t] = (r < 64) ? (__f16)xpw[layer * 65536 + r * 1024 + k] : (__f16)0.f;
}

// pack whh f32 -> f16 uint4, layout [dir][gate G][q][t] with t=(j<<1)|ks
__global__ __launch_bounds__(256) void pack_whh(
    const float* __restrict__ whh, uint4* __restrict__ wpk)
{
  int idx = blockIdx.x * 256 + threadIdx.x;   // [0, 65536)
  int t = idx & 511;
  int q = (idx >> 9) & 15;
  int G = (idx >> 13) & 3;
  int dir = idx >> 15;
  int j = t >> 1, ks = t & 1;
  const float* src = whh + (size_t)dir * 262144 + (size_t)(G * 256 + j) * 256 + ks * 128 + q * 8;
  float4 fa = ((const float4*)src)[0];
  float4 fb = ((const float4*)src)[1];
  uint4 pk;
  pk.x = packf16(fa.x, fa.y); pk.y = packf16(fa.z, fa.w);
  pk.z = packf16(fb.x, fb.y); pk.w = packf16(fb.z, fb.w);
  wpk[idx] = pk;
}

// u[b,l,c] = silu(cb[c] + conv(xin)); dual write f32 + f16
__global__ __launch_bounds__(256) void conv_silu(
    const float* __restrict__ xz, const float* __restrict__ cw, const float* __restrict__ cb,
    float* __restrict__ u, __f16* __restrict__ uh)
{
  int t = blockIdx.x * 256 + threadIdx.x;
  int c  = t & (DIN - 1);
  int bl = t >> 10;
  int l  = bl & (L_ - 1);
  float acc = cb[c];
  #pragma unroll
  for (int k = 0; k < DCV; ++k) {
    int ls = l + k - (DCV - 1);
    if (ls >= 0)
      acc = fmaf(xz[(size_t)(bl + k - (DCV - 1)) * 2048 + c], cw[c * DCV + k], acc);
  }
  float v = acc * fast_sigmoid(acc);
  u[t] = v;
  uh[t] = (__f16)v;
}

// selective scan: thread per (b,c,n); 4-deep rotating prefetch; f16 y out
__global__ __launch_bounds__(256) void scan_kernel(
    const float* __restrict__ dt, const float* __restrict__ u,
    const float* __restrict__ xdbl, const float* __restrict__ xz,
    const float* __restrict__ A_log, const float* __restrict__ Dp,
    __f16* __restrict__ y)
{
  int t = blockIdx.x * 256 + threadIdx.x;
  int n  = t & 15;
  int bc = t >> 4;
  int c  = bc & (DIN - 1);
  int b  = bc >> 10;
  float Ac = -__expf(A_log[c * DST + n]);
  float Dc = Dp[c];
  float h = 0.f;
  const size_t row = (size_t)b * L_;

#define DECLP(i) float dtv##i, uv##i, Bn##i, Cn##i, zv##i;
  DECLP(0) DECLP(1) DECLP(2) DECLP(3)
#define LOADP(i, l) { \
    const size_t nb_ = row + (l); \
    dtv##i = dt[nb_ * DIN + c]; \
    uv##i  = u [nb_ * DIN + c]; \
    Bn##i  = xdbl[nb_ * 128 + 32 + n]; \
    Cn##i  = xdbl[nb_ * 128 + 48 + n]; \
    zv##i  = xz[nb_ * 2048 + 1024 + c]; }
#define STEPP(i, l) { \
    float dA_ = __expf(dtv##i * Ac); \
    h = fmaf(dA_, h, (dtv##i * uv##i) * Bn##i); \
    float p_ = h * Cn##i; \
    p_ += __shfl_xor(p_, 1, 64); \
    p_ += __shfl_xor(p_, 2, 64); \
    p_ += __shfl_xor(p_, 4, 64); \
    p_ += __shfl_xor(p_, 8, 64); \
    if (n == 0) { \
      float yv_ = p_ + uv##i * Dc; \
      yv_ *= zv##i * fast_sigmoid(zv##i); \
      y[(row + (l)) * DIN + c] = (__f16)yv_; \
    } }

  LOADP(0, 0) LOADP(1, 1) LOADP(2, 2) LOADP(3, 3)
  for (int l = 0; l < L_ - 4; l += 4) {
    STEPP(0, l)     LOADP(0, l + 4)
    STEPP(1, l + 1) LOADP(1, l + 5)
    STEPP(2, l + 2) LOADP(2, l + 6)
    STEPP(3, l + 3) LOADP(3, l + 7)
  }
  STEPP(0, L_ - 4) STEPP(1, L_ - 3) STEPP(2, L_ - 2) STEPP(3, L_ - 1)
#undef DECLP
#undef LOADP
#undef STEPP
}

// layernorm(a + mo)*g + b -> optional f32 out + f16 out
__global__ __launch_bounds__(64) void resid_ln(
    const float* __restrict__ a, const float* __restrict__ mo,
    const float* __restrict__ g, const float* __restrict__ bta,
    float* __restrict__ outm, int ldo, __f16* __restrict__ outh, int ldoh)
{
  int row = blockIdx.x;
  int lane = threadIdx.x;
  const float* pa = a  + (size_t)row * 512;
  const float* pb = mo + (size_t)row * 512;
  float v[8];
  float s = 0.f, s2 = 0.f;
  #pragma unroll
  for (int i = 0; i < 8; ++i) {
    float x = pa[lane + i * 64] + pb[lane + i * 64];
    v[i] = x; s += x; s2 += x * x;
  }
  #pragma unroll
  for (int off = 1; off < 64; off <<= 1) {
    s  += __shfl_xor(s,  off, 64);
    s2 += __shfl_xor(s2, off, 64);
  }
  float mean = s * (1.f / 512.f);
  float var  = s2 * (1.f / 512.f) - mean * mean;
  float rstd = rsqrtf(var + 1e-5f);
  #pragma unroll
  for (int i = 0; i < 8; ++i) {
    int cidx = lane + i * 64;
    float o = (v[i] - mean) * rstd * g[cidx] + bta[cidx];
    if (outm) outm[(size_t)row * ldo + cidx] = o;
    outh[(size_t)row * ldoh + cidx] = (__f16)o;
  }
}

// ---------------- LSTM recurrence (r13 structure, empirical best 825us) ----------------
#define WDECL(q) uint4 W0_##q, W1_##q, W2_##q;
#define LDG1(W, G, q) W = wp[((G) * 16 + (q)) * 512 + t];
#define WLOAD(q) LDG1(W0_##q, 0, q) LDG1(W1_##q, 1, q) LDG1(W2_##q, 2, q)
#define WSTEP(q) { \
    uint4 hv = h4s[buf][(q) * 2 + ks]; \
    uint4 wv = wo_lds[(q) * 512 + t]; \
    a0 = dot2f(W0_##q.x, hv.x, a0); a0 = dot2f(W0_##q.y, hv.y, a0); \
    a0 = dot2f(W0_##q.z, hv.z, a0); a0 = dot2f(W0_##q.w, hv.w, a0); \
    a1 = dot2f(W1_##q.x, hv.x, a1); a1 = dot2f(W1_##q.y, hv.y, a1); \
    a1 = dot2f(W1_##q.z, hv.z, a1); a1 = dot2f(W1_##q.w, hv.w, a1); \
    a2 = dot2f(W2_##q.x, hv.x, a2); a2 = dot2f(W2_##q.y, hv.y, a2); \
    a2 = dot2f(W2_##q.z, hv.z, a2); a2 = dot2f(W2_##q.w, hv.w, a2); \
    a3 = dot2f(wv.x, hv.x, a3); a3 = dot2f(wv.y, hv.y, a3); \
    a3 = dot2f(wv.z, hv.z, a3); a3 = dot2f(wv.w, hv.w, a3); }
#define REP16(M) M(0) M(1) M(2) M(3) M(4) M(5) M(6) M(7) \
                 M(8) M(9) M(10) M(11) M(12) M(13) M(14) M(15)

__global__ __launch_bounds__(512, 1) void lstm_rec(
    const float* __restrict__ gx, const uint4* __restrict__ wpk,
    __f16* __restrict__ comb)
{
  __shared__ uint4 wo_lds[16 * 512];
  __shared__ __align__(16) uint4 h4s[2][32];
  const int dir = blockIdx.x >> 2, b = blockIdx.x & 3;
  const int t = threadIdx.x;
  const int j = t >> 1, ks = t & 1;
  const uint4* wp = wpk + (size_t)dir * 4 * 16 * 512;

  REP16(WDECL)
  REP16(WLOAD)

  #pragma unroll
  for (int q = 0; q < 16; ++q)
    wo_lds[q * 512 + t] = wp[(3 * 16 + q) * 512 + t];

  if (t < 256) ((unsigned*)h4s)[t] = 0u;
  float c_reg = 0.f;
  __f16* outp = comb + 512 + dir * 256;
  const float* gxb = gx + (size_t)(b * L_) * 2048 + dir * 1024;
  const int offA = (ks ? 1 : 0) * 256 + j;
  const int offB = (ks ? 3 : 2) * 256 + j;
  const int p_   = t >> 2;
  const int hidx = ((p_ >> 2) & 15) * 8 + (p_ >> 6) * 4 + (p_ & 3);
  __syncthreads();

  int buf = 0;
  const int l0 = dir ? (L_ - 1) : 0;
  float pgA = gxb[(size_t)l0 * 2048 + offA];
  float pgB = gxb[(size_t)l0 * 2048 + offB];

  for (int s = 0; s < L_; ++s) {
    const int l = dir ? (L_ - 1 - s) : s;
    float pgA_n = 0.f, pgB_n = 0.f;
    if (s + 1 < L_) {
      const int ln = dir ? (L_ - 2 - s) : (s + 1);
      pgA_n = gxb[(size_t)ln * 2048 + offA];
      pgB_n = gxb[(size_t)ln * 2048 + offB];
    }
    float a0 = 0.f, a1 = 0.f, a2 = 0.f, a3 = 0.f;
    REP16(WSTEP)
    if (ks == 0) { a0 += pgA; a2 += pgB; } else { a1 += pgA; a3 += pgB; }
    a0 += __shfl_xor(a0, 1, 64);
    a1 += __shfl_xor(a1, 1, 64);
    a2 += __shfl_xor(a2, 1, 64);
    a3 += __shfl_xor(a3, 1, 64);
    const float si = fast_sigmoid(a0);
    const float sf = fast_sigmoid(a1);
    const float tg = fast_tanh(a2);
    const float so = fast_sigmoid(a3);
    c_reg = fmaf(sf, c_reg, si * tg);
    const float hv = so * fast_tanh(c_reg);
    if (ks == 0) outp[(size_t)(b * L_ + l) * 1024 + j] = (__f16)hv;
    const float hv2 = __shfl_xor(hv, 2, 64);
    if ((t & 3) == 0)
      ((unsigned*)h4s[buf ^ 1])[hidx] = packf16(hv, hv2);
    pgA = pgA_n; pgB = pgB_n;
    buf ^= 1;
    __syncthreads();
  }
}

extern "C" void kernel_launch(void* const* d_in, const int* in_sizes, int n_in,
                              void* d_out, int out_size, void* d_ws, size_t ws_size,
                              hipStream_t stream)
{
  const float* x    = (const float*)d_in[0];
  const float* wi   = (const float*)d_in[1];
  const float* cw   = (const float*)d_in[2];
  const float* cb   = (const float*)d_in[3];
  const float* xpw  = (const float*)d_in[4];
  const float* dw   = (const float*)d_in[5];
  const float* db   = (const float*)d_in[6];
  const float* Alog = (const float*)d_in[7];
  const float* Dp   = (const float*)d_in[8];
  const float* wo   = (const float*)d_in[9];
  const float* lng  = (const float*)d_in[10];
  const float* lnb  = (const float*)d_in[11];
  const float* wih  = (const float*)d_in[12];
  const float* whh  = (const float*)d_in[13];
  const float* bih  = (const float*)d_in[14];
  const float* bhh  = (const float*)d_in[15];
  const float* fw   = (const float*)d_in[16];
  const float* fb   = (const float*)d_in[17];
  float* out = (float*)d_out;

  float* F = (float*)d_ws;
  // f32 buffers
  float* xz     = F;                       // 4,194,304 (gx aliases; mo lives at +3,145,728)
  float* gx     = F;
  float* mo     = F + 3145728;             // 1,048,576 (inside xz; safe: written after scan, read before next xz)
  float* u      = F + 4194304;             // 2,097,152
  float* xdbl   = F + 7340032;             //   262,144
  float* dt     = F + 7602176;             // 2,097,152
  float* mbuf   = F + 10747904;            // 1,048,576
  // f16 / packed buffers (aliased into dead windows)
  __f16* fw_h   = (__f16*)(F + 4194304);   // in u region, packed after last u use
  __f16* u_h    = (__f16*)(F + 6291456);   // 2,097,152 halves
  __f16* wih_h  = (__f16*)(F + 7602176);   // in dt region (dead until first dt write)
  uint4* wpk    = (uint4*)(F + 8126464);   // in dt region
  __f16* wi_hc  = (__f16*)(F + 8388608);   // in dt region, repacked per layer
  __f16* ybuf_h = (__f16*)(F + 9699328);   // 2,097,152 halves
  __f16* x_h    = (__f16*)(F + 9699328);   // aliases ybuf_h (dead before first scan)
  __f16* mbuf_h = (__f16*)(F + 11796480);  // 1,048,576 halves
  __f16* comb_h = (__f16*)(F + 12320768);  // 2,097,152 halves [m | lf | lb], ld 1024
  __f16* wo_h   = (__f16*)(F + 13369344);  // 1,572,864 halves
  __f16* xpw_h  = (__f16*)(F + 14155776);  //   393,216 halves

  const int M = B_ * L_;                   // 2048
  dim3 blk(256);

  // one-time f16 packs
  packh<<<dim3(4096), blk, 0, stream>>>(x,   x_h,   1048576);
  packh<<<dim3(4096), blk, 0, stream>>>(wih, wih_h, 1048576);
  packh<<<dim3(6144), blk, 0, stream>>>(wo,  wo_h,  1572864);
  pack_xpw_h<<<dim3(1536), blk, 0, stream>>>(xpw, xpw_h);

  // LSTM input projection + recurrence
  gemm_mfma_h<false><<<dim3(16, 16), blk, 0, stream>>>(
      x_h, wih_h, gx, M, 2048, 512, 512, 512, 2048, bih, bhh);
  pack_whh<<<dim3(256), blk, 0, stream>>>(whh, wpk);
  lstm_rec<<<dim3(8), dim3(512), 0, stream>>>(gx, wpk, comb_h);

  for (int i = 0; i < NL; ++i) {
    const float* min = (i == 0) ? x : mbuf;
    const __f16* min_h = (i == 0) ? x_h : mbuf_h;
    packh<<<dim3(4096), blk, 0, stream>>>(wi + (size_t)i*1048576, wi_hc, 1048576);
    // xz = m @ in_proj^T
    gemm_mfma_h<false><<<dim3(16, 16), blk, 0, stream>>>(
        min_h, wi_hc, xz, M, 2048, 512, 512, 512, 2048, nullptr, nullptr);
    // u = silu(conv(xin)+cb)  (f32 + f16)
    conv_silu<<<dim3(8192), blk, 0, stream>>>(
        xz, cw + (size_t)i*DIN*DCV, cb + i*DIN, u, u_h);
    // xdbl = u @ xpw_pad^T
    gemm_mfma_h<false><<<dim3(1, 16), blk, 0, stream>>>(
        u_h, xpw_h + (size_t)i*131072, xdbl, M, 128, 1024, 1024, 1024, 128, nullptr, nullptr);
    // dt = softplus(dt_in @ dt_proj^T + db)
    gemm_nt<1><<<dim3(16, 32), blk, 0, stream>>>(
        xdbl, dw + (size_t)i*32768, dt, M, 1024, 32, 128, 32, 1024, db + i*1024);
    // scan -> ybuf (f16)
    scan_kernel<<<dim3(256), blk, 0, stream>>>(
        dt, u, xdbl, xz, Alog + (size_t)i*DIN*DST, Dp + i*DIN, ybuf_h);
    // mo = y @ out_proj^T
    gemm_mfma_h<false><<<dim3(4, 16), blk, 0, stream>>>(
        ybuf_h, wo_h + (size_t)i*524288, mo, M, 512, 1024, 1024, 1024, 512, nullptr, nullptr);
    // m = LN(m + mo): layers 0,1 -> mbuf(+h); layer 2 -> comb cols [0,512)
    if (i < NL - 1)
      resid_ln<<<dim3(M), dim3(64), 0, stream>>>(
          min, mo, lng + i*512, lnb + i*512, mbuf, 512, mbuf_h, 512);
    else
      resid_ln<<<dim3(M), dim3(64), 0, stream>>>(
          min, mo, lng + i*512, lnb + i*512, nullptr, 0, comb_h, 1024);
  }

  // fusion: out = comb @ fusion_w^T + fb
  packh<<<dim3(2048), blk, 0, stream>>>(fw, fw_h, 524288);
  gemm_mfma_h<false><<<dim3(4, 16), blk, 0, stream>>>(
      comb_h, fw_h, out, M, 512, 1024, 1024, 1024, 512, fb, nullptr);
}

// Round 16
// 1426.444 us; speedup vs baseline: 4.2022x; 1.0896x over previous
//
#include <hip/hip_runtime.h>
#include <math.h>

#define B_  4
#define L_  512
#define D_  512
#define DIN 1024
#define DST 16
#define DCV 4
#define DTR 32
#define NL  3
#define H2  256
#define LCH 128   // scan chunk length

typedef _Float16 __f16;
typedef __f16 f16x2 __attribute__((ext_vector_type(2)));
typedef __f16 half8 __attribute__((ext_vector_type(8)));
typedef float f32x4v __attribute__((ext_vector_type(4)));
typedef unsigned uint4v __attribute__((ext_vector_type(4)));

__device__ __forceinline__ float fast_sigmoid(float x) { return 1.f / (1.f + __expf(-x)); }
__device__ __forceinline__ float fast_tanh(float x) { return 2.f / (1.f + __expf(-2.f * x)) - 1.f; }

__device__ __forceinline__ float dot2f(unsigned a, unsigned b, float c) {
  return __builtin_amdgcn_fdot2(__builtin_bit_cast(f16x2, a),
                                __builtin_bit_cast(f16x2, b), c, false);
}
__device__ __forceinline__ unsigned packf16(float a, float b) {
  f16x2 p; p.x = (__f16)a; p.y = (__f16)b;
  return __builtin_bit_cast(unsigned, p);
}

// ---------------- f16-operand MFMA GEMM ----------------
// C = act(A[M,K] @ W[N,K]^T + bias + bias2). ACT: 0 none, 1 softplus.
// HOUT: write f16 output instead of f32.
template<int ACT, bool ACC, bool HOUT>
__global__ __launch_bounds__(256) void gemm_mfma_h(
    const __f16* __restrict__ A, const __f16* __restrict__ W, void* __restrict__ Cv,
    int M, int N, int K, int lda, int ldb, int ldc,
    const float* __restrict__ bias, const float* __restrict__ bias2)
{
  __shared__ uint4v As[1024];   // [row][8 kb-slots], phys slot = kb ^ (row&7)
  __shared__ uint4v Bs[1024];
  const int tid  = threadIdx.x;
  const int lane = tid & 63, wid = tid >> 6;
  const int wr = wid >> 1, wc = wid & 1;
  const int fr = lane & 15, fq = lane >> 4;
  const int m0 = blockIdx.y * 128, n0 = blockIdx.x * 128;
  const int srow = tid >> 3, skb = tid & 7;

  f32x4v acc[4][4] = {};
  for (int k0 = 0; k0 < K; k0 += 64) {
    const __f16* Ab = A + (size_t)m0 * lda + k0;
    const __f16* Bb = W + (size_t)n0 * ldb + k0;
    #pragma unroll
    for (int i = 0; i < 4; ++i) {
      int row = srow + i * 32;
      uint4v ap = *(const uint4v*)(Ab + (size_t)row * lda + skb * 8);
      uint4v bp = *(const uint4v*)(Bb + (size_t)row * ldb + skb * 8);
      As[row * 8 + (skb ^ (row & 7))] = ap;
      Bs[row * 8 + (skb ^ (row & 7))] = bp;
    }
    __syncthreads();
    #pragma unroll
    for (int ks = 0; ks < 2; ++ks) {
      half8 af[4], bf[4];
      #pragma unroll
      for (int mt = 0; mt < 4; ++mt) {
        int row = wr * 64 + mt * 16 + fr;
        int kb = ks * 4 + fq;
        af[mt] = __builtin_bit_cast(half8, As[row * 8 + (kb ^ (row & 7))]);
      }
      #pragma unroll
      for (int nt = 0; nt < 4; ++nt) {
        int row = wc * 64 + nt * 16 + fr;
        int kb = ks * 4 + fq;
        bf[nt] = __builtin_bit_cast(half8, Bs[row * 8 + (kb ^ (row & 7))]);
      }
      #pragma unroll
      for (int mt = 0; mt < 4; ++mt)
        #pragma unroll
        for (int nt = 0; nt < 4; ++nt)
          acc[mt][nt] = __builtin_amdgcn_mfma_f32_16x16x32_f16(af[mt], bf[nt], acc[mt][nt], 0, 0, 0);
    }
    __syncthreads();
  }
  float* C = (float*)Cv;
  __f16* Ch = (__f16*)Cv;
  #pragma unroll
  for (int nt = 0; nt < 4; ++nt) {
    int n = n0 + wc * 64 + nt * 16 + fr;
    float bv = (bias ? bias[n] : 0.f) + (bias2 ? bias2[n] : 0.f);
    #pragma unroll
    for (int mt = 0; mt < 4; ++mt) {
      #pragma unroll
      for (int r = 0; r < 4; ++r) {
        int m = m0 + wr * 64 + mt * 16 + fq * 4 + r;
        float v = acc[mt][nt][r] + bv;
        if (ACT == 1) v = (v > 20.f) ? v : log1pf(__expf(v));
        if (HOUT) Ch[(size_t)m * ldc + n] = (__f16)v;
        else if (ACC) C[(size_t)m * ldc + n] += v;
        else C[(size_t)m * ldc + n] = v;
      }
    }
  }
}

// generic f32 -> f16 pack
__global__ __launch_bounds__(256) void packh(
    const float* __restrict__ src, __f16* __restrict__ dst, int n)
{
  int t = blockIdx.x * 256 + threadIdx.x;
  if (t < n) dst[t] = (__f16)src[t];
}

// all 3 layers' x_proj weights, zero-padded 64->128 rows, packed f16
__global__ __launch_bounds__(256) void pack_xpw_h(
    const float* __restrict__ xpw, __f16* __restrict__ dst)
{
  int t = blockIdx.x * 256 + threadIdx.x;   // [0, 3*131072)
  int layer = t >> 17;
  int r = (t >> 10) & 127;
  int k = t & 1023;
  dst[t] = (r < 64) ? (__f16)xpw[layer * 65536 + r * 1024 + k] : (__f16)0.f;
}

// all 3 layers' dt_proj weights, zero-padded K 32->64, packed f16: [layer][1024][64]
__global__ __launch_bounds__(256) void pack_dwh(
    const float* __restrict__ dw, __f16* __restrict__ dst)
{
  int t = blockIdx.x * 256 + threadIdx.x;   // [0, 3*65536)
  int layer = t >> 16;
  int r = (t >> 6) & 1023;
  int k = t & 63;
  dst[t] = (k < 32) ? (__f16)dw[layer * 32768 + r * 32 + k] : (__f16)0.f;
}

// pack whh f32 -> f16 uint4, layout [dir][gate G][q][t] with t=(j<<1)|ks
__global__ __launch_bounds__(256) void pack_whh(
    const float* __restrict__ whh, uint4* __restrict__ wpk)
{
  int idx = blockIdx.x * 256 + threadIdx.x;   // [0, 65536)
  int t = idx & 511;
  int q = (idx >> 9) & 15;
  int G = (idx >> 13) & 3;
  int dir = idx >> 15;
  int j = t >> 1, ks = t & 1;
  const float* src = whh + (size_t)dir * 262144 + (size_t)(G * 256 + j) * 256 + ks * 128 + q * 8;
  float4 fa = ((const float4*)src)[0];
  float4 fb = ((const float4*)src)[1];
  uint4 pk;
  pk.x = packf16(fa.x, fa.y); pk.y = packf16(fa.z, fa.w);
  pk.z = packf16(fb.x, fb.y); pk.w = packf16(fb.z, fb.w);
  wpk[idx] = pk;
}

// u[b,l,c] = silu(cb[c] + conv(xin)); dual write f32 + f16
__global__ __launch_bounds__(256) void conv_silu(
    const float* __restrict__ xz, const float* __restrict__ cw, const float* __restrict__ cb,
    float* __restrict__ u, __f16* __restrict__ uh)
{
  int t = blockIdx.x * 256 + threadIdx.x;
  int c  = t & (DIN - 1);
  int bl = t >> 10;
  int l  = bl & (L_ - 1);
  float acc = cb[c];
  #pragma unroll
  for (int k = 0; k < DCV; ++k) {
    int ls = l + k - (DCV - 1);
    if (ls >= 0)
      acc = fmaf(xz[(size_t)(bl + k - (DCV - 1)) * 2048 + c], cw[c * DCV + k], acc);
  }
  float v = acc * fast_sigmoid(acc);
  u[t] = v;
  uh[t] = (__f16)v;
}

// ---------------- chunked selective scan ----------------
// thread = (b, c, ch, n): t&15 = n, (t>>4)&3 = ch, t>>6 = b*1024+c.
// 262144 threads -> 4 waves/SIMD (vs 1 for the monolithic scan).
// Pass A: local scan of chunk ch from h0=0 -> (h_end, P=prod dA).
// Pass B: fold <=3 predecessor summaries into the true start state, re-run
// chunk producing y. Linearity of h_l = dA*h_{l-1} + b_l makes this exact.

__global__ __launch_bounds__(256) void scan_part(
    const float* __restrict__ dt, const float* __restrict__ u,
    const __f16* __restrict__ xdh, const float* __restrict__ A_log,
    float* __restrict__ hend, float* __restrict__ Pp)
{
  int t = blockIdx.x * 256 + threadIdx.x;   // [0, 262144)
  int n  = t & 15;
  int ch = (t >> 4) & 3;
  int bc = t >> 6;
  int c  = bc & (DIN - 1);
  int b  = bc >> 10;
  float Ac = -__expf(A_log[c * DST + n]);
  float h = 0.f, P = 1.f;
  const size_t row = (size_t)b * L_ + ch * LCH;

#define DECLP(i) float dtv##i, uv##i, Bn##i;
  DECLP(0) DECLP(1) DECLP(2) DECLP(3)
#define LOADP(i, l) { \
    const size_t nb_ = row + (l); \
    dtv##i = dt[nb_ * DIN + c]; \
    uv##i  = u [nb_ * DIN + c]; \
    Bn##i  = (float)xdh[nb_ * 128 + 32 + n]; }
#define STEPP(i) { \
    float dA_ = __expf(dtv##i * Ac); \
    h = fmaf(dA_, h, (dtv##i * uv##i) * Bn##i); \
    P *= dA_; }

  LOADP(0, 0) LOADP(1, 1) LOADP(2, 2) LOADP(3, 3)
  for (int l = 0; l < LCH - 4; l += 4) {
    STEPP(0) LOADP(0, l + 4)
    STEPP(1) LOADP(1, l + 5)
    STEPP(2) LOADP(2, l + 6)
    STEPP(3) LOADP(3, l + 7)
  }
  STEPP(0) STEPP(1) STEPP(2) STEPP(3)
#undef DECLP
#undef LOADP
#undef STEPP
  int flat = bc * 16 + n;
  hend[ch * 65536 + flat] = h;
  Pp[ch * 65536 + flat]   = P;
}

__global__ __launch_bounds__(256) void scan_fix(
    const float* __restrict__ dt, const float* __restrict__ u,
    const __f16* __restrict__ xdh, const float* __restrict__ xz,
    const float* __restrict__ A_log, const float* __restrict__ Dp,
    const float* __restrict__ hend, const float* __restrict__ Pp,
    __f16* __restrict__ y)
{
  int t = blockIdx.x * 256 + threadIdx.x;   // [0, 262144)
  int n  = t & 15;
  int ch = (t >> 4) & 3;
  int bc = t >> 6;
  int c  = bc & (DIN - 1);
  int b  = bc >> 10;
  float Ac = -__expf(A_log[c * DST + n]);
  float Dc = Dp[c];
  const int flat = bc * 16 + n;
  // fold predecessor chunk summaries into the true start state
  float h = 0.f;
  if (ch > 0) h = hend[flat];
  if (ch > 1) h = fmaf(Pp[1 * 65536 + flat], h, hend[1 * 65536 + flat]);
  if (ch > 2) h = fmaf(Pp[2 * 65536 + flat], h, hend[2 * 65536 + flat]);
  const size_t row = (size_t)b * L_ + ch * LCH;

#define DECLP(i) float dtv##i, uv##i, Bn##i, Cn##i, zv##i;
  DECLP(0) DECLP(1) DECLP(2) DECLP(3)
#define LOADP(i, l) { \
    const size_t nb_ = row + (l); \
    dtv##i = dt[nb_ * DIN + c]; \
    uv##i  = u [nb_ * DIN + c]; \
    Bn##i  = (float)xdh[nb_ * 128 + 32 + n]; \
    Cn##i  = (float)xdh[nb_ * 128 + 48 + n]; \
    zv##i  = xz[nb_ * 2048 + 1024 + c]; }
#define STEPP(i, l) { \
    float dA_ = __expf(dtv##i * Ac); \
    h = fmaf(dA_, h, (dtv##i * uv##i) * Bn##i); \
    float p_ = h * Cn##i; \
    p_ += __shfl_xor(p_, 1, 64); \
    p_ += __shfl_xor(p_, 2, 64); \
    p_ += __shfl_xor(p_, 4, 64); \
    p_ += __shfl_xor(p_, 8, 64); \
    if (n == 0) { \
      float yv_ = p_ + uv##i * Dc; \
      yv_ *= zv##i * fast_sigmoid(zv##i); \
      y[(row + (l)) * DIN + c] = (__f16)yv_; \
    } }

  LOADP(0, 0) LOADP(1, 1) LOADP(2, 2) LOADP(3, 3)
  for (int l = 0; l < LCH - 4; l += 4) {
    STEPP(0, l)     LOADP(0, l + 4)
    STEPP(1, l + 1) LOADP(1, l + 5)
    STEPP(2, l + 2) LOADP(2, l + 6)
    STEPP(3, l + 3) LOADP(3, l + 7)
  }
  STEPP(0, LCH - 4) STEPP(1, LCH - 3) STEPP(2, LCH - 2) STEPP(3, LCH - 1)
#undef DECLP
#undef LOADP
#undef STEPP
}

// layernorm(a + mo)*g + b -> optional f32 out + f16 out
__global__ __launch_bounds__(64) void resid_ln(
    const float* __restrict__ a, const float* __restrict__ mo,
    const float* __restrict__ g, const float* __restrict__ bta,
    float* __restrict__ outm, int ldo, __f16* __restrict__ outh, int ldoh)
{
  int row = blockIdx.x;
  int lane = threadIdx.x;
  const float* pa = a  + (size_t)row * 512;
  const float* pb = mo + (size_t)row * 512;
  float v[8];
  float s = 0.f, s2 = 0.f;
  #pragma unroll
  for (int i = 0; i < 8; ++i) {
    float x = pa[lane + i * 64] + pb[lane + i * 64];
    v[i] = x; s += x; s2 += x * x;
  }
  #pragma unroll
  for (int off = 1; off < 64; off <<= 1) {
    s  += __shfl_xor(s,  off, 64);
    s2 += __shfl_xor(s2, off, 64);
  }
  float mean = s * (1.f / 512.f);
  float var  = s2 * (1.f / 512.f) - mean * mean;
  float rstd = rsqrtf(var + 1e-5f);
  #pragma unroll
  for (int i = 0; i < 8; ++i) {
    int cidx = lane + i * 64;
    float o = (v[i] - mean) * rstd * g[cidx] + bta[cidx];
    if (outm) outm[(size_t)row * ldo + cidx] = o;
    outh[(size_t)row * ldoh + cidx] = (__f16)o;
  }
}

// ---------------- LSTM recurrence (r13 structure, empirical best 825us) ----------------
#define WDECL(q) uint4 W0_##q, W1_##q, W2_##q;
#define LDG1(W, G, q) W = wp[((G) * 16 + (q)) * 512 + t];
#define WLOAD(q) LDG1(W0_##q, 0, q) LDG1(W1_##q, 1, q) LDG1(W2_##q, 2, q)
#define WSTEP(q) { \
    uint4 hv = h4s[buf][(q) * 2 + ks]; \
    uint4 wv = wo_lds[(q) * 512 + t]; \
    a0 = dot2f(W0_##q.x, hv.x, a0); a0 = dot2f(W0_##q.y, hv.y, a0); \
    a0 = dot2f(W0_##q.z, hv.z, a0); a0 = dot2f(W0_##q.w, hv.w, a0); \
    a1 = dot2f(W1_##q.x, hv.x, a1); a1 = dot2f(W1_##q.y, hv.y, a1); \
    a1 = dot2f(W1_##q.z, hv.z, a1); a1 = dot2f(W1_##q.w, hv.w, a1); \
    a2 = dot2f(W2_##q.x, hv.x, a2); a2 = dot2f(W2_##q.y, hv.y, a2); \
    a2 = dot2f(W2_##q.z, hv.z, a2); a2 = dot2f(W2_##q.w, hv.w, a2); \
    a3 = dot2f(wv.x, hv.x, a3); a3 = dot2f(wv.y, hv.y, a3); \
    a3 = dot2f(wv.z, hv.z, a3); a3 = dot2f(wv.w, hv.w, a3); }
#define REP16(M) M(0) M(1) M(2) M(3) M(4) M(5) M(6) M(7) \
                 M(8) M(9) M(10) M(11) M(12) M(13) M(14) M(15)

__global__ __launch_bounds__(512, 1) void lstm_rec(
    const float* __restrict__ gx, const uint4* __restrict__ wpk,
    __f16* __restrict__ comb)
{
  __shared__ uint4 wo_lds[16 * 512];
  __shared__ __align__(16) uint4 h4s[2][32];
  const int dir = blockIdx.x >> 2, b = blockIdx.x & 3;
  const int t = threadIdx.x;
  const int j = t >> 1, ks = t & 1;
  const uint4* wp = wpk + (size_t)dir * 4 * 16 * 512;

  REP16(WDECL)
  REP16(WLOAD)

  #pragma unroll
  for (int q = 0; q < 16; ++q)
    wo_lds[q * 512 + t] = wp[(3 * 16 + q) * 512 + t];

  if (t < 256) ((unsigned*)h4s)[t] = 0u;
  float c_reg = 0.f;
  __f16* outp = comb + 512 + dir * 256;
  const float* gxb = gx + (size_t)(b * L_) * 2048 + dir * 1024;
  const int offA = (ks ? 1 : 0) * 256 + j;
  const int offB = (ks ? 3 : 2) * 256 + j;
  const int p_   = t >> 2;
  const int hidx = ((p_ >> 2) & 15) * 8 + (p_ >> 6) * 4 + (p_ & 3);
  __syncthreads();

  int buf = 0;
  const int l0 = dir ? (L_ - 1) : 0;
  float pgA = gxb[(size_t)l0 * 2048 + offA];
  float pgB = gxb[(size_t)l0 * 2048 + offB];

  for (int s = 0; s < L_; ++s) {
    const int l = dir ? (L_ - 1 - s) : s;
    float pgA_n = 0.f, pgB_n = 0.f;
    if (s + 1 < L_) {
      const int ln = dir ? (L_ - 2 - s) : (s + 1);
      pgA_n = gxb[(size_t)ln * 2048 + offA];
      pgB_n = gxb[(size_t)ln * 2048 + offB];
    }
    float a0 = 0.f, a1 = 0.f, a2 = 0.f, a3 = 0.f;
    REP16(WSTEP)
    if (ks == 0) { a0 += pgA; a2 += pgB; } else { a1 += pgA; a3 += pgB; }
    a0 += __shfl_xor(a0, 1, 64);
    a1 += __shfl_xor(a1, 1, 64);
    a2 += __shfl_xor(a2, 1, 64);
    a3 += __shfl_xor(a3, 1, 64);
    const float si = fast_sigmoid(a0);
    const float sf = fast_sigmoid(a1);
    const float tg = fast_tanh(a2);
    const float so = fast_sigmoid(a3);
    c_reg = fmaf(sf, c_reg, si * tg);
    const float hv = so * fast_tanh(c_reg);
    if (ks == 0) outp[(size_t)(b * L_ + l) * 1024 + j] = (__f16)hv;
    const float hv2 = __shfl_xor(hv, 2, 64);
    if ((t & 3) == 0)
      ((unsigned*)h4s[buf ^ 1])[hidx] = packf16(hv, hv2);
    pgA = pgA_n; pgB = pgB_n;
    buf ^= 1;
    __syncthreads();
  }
}

extern "C" void kernel_launch(void* const* d_in, const int* in_sizes, int n_in,
                              void* d_out, int out_size, void* d_ws, size_t ws_size,
                              hipStream_t stream)
{
  const float* x    = (const float*)d_in[0];
  const float* wi   = (const float*)d_in[1];
  const float* cw   = (const float*)d_in[2];
  const float* cb   = (const float*)d_in[3];
  const float* xpw  = (const float*)d_in[4];
  const float* dw   = (const float*)d_in[5];
  const float* db   = (const float*)d_in[6];
  const float* Alog = (const float*)d_in[7];
  const float* Dp   = (const float*)d_in[8];
  const float* wo   = (const float*)d_in[9];
  const float* lng  = (const float*)d_in[10];
  const float* lnb  = (const float*)d_in[11];
  const float* wih  = (const float*)d_in[12];
  const float* whh  = (const float*)d_in[13];
  const float* bih  = (const float*)d_in[14];
  const float* bhh  = (const float*)d_in[15];
  const float* fw   = (const float*)d_in[16];
  const float* fb   = (const float*)d_in[17];
  float* out = (float*)d_out;

  float* F = (float*)d_ws;
  // f32 buffers
  float* xz     = F;                       // 4,194,304 (gx aliases; mo at +3,145,728)
  float* gx     = F;
  float* mo     = F + 3145728;             // 1,048,576
  float* u      = F + 4194304;             // 2,097,152
  __f16* xdh    = (__f16*)(F + 7340032);   // 262,144 halves (xdbl f16, ld 128)
  float* dt     = F + 7602176;             // 2,097,152
  float* mbuf   = F + 10747904;            // 1,048,576
  // f16 / packed buffers (aliased into dead windows)
  __f16* fw_h   = (__f16*)(F + 4194304);   // in u region, packed after last u use
  __f16* u_h    = (__f16*)(F + 6291456);   // 2,097,152 halves
  __f16* wih_h  = (__f16*)(F + 7602176);   // in dt region (dead until first dt write)
  uint4* wpk    = (uint4*)(F + 8126464);   // in dt region
  __f16* wi_hc  = (__f16*)(F + 8388608);   // in dt region, repacked per layer
  __f16* ybuf_h = (__f16*)(F + 9699328);   // 2,097,152 halves
  __f16* x_h    = (__f16*)(F + 9699328);   // aliases ybuf_h (dead before first scan)
  __f16* mbuf_h = (__f16*)(F + 11796480);  // 1,048,576 halves
  __f16* comb_h = (__f16*)(F + 12320768);  // 2,097,152 halves [m | lf | lb], ld 1024
  __f16* wo_h   = (__f16*)(F + 13369344);  // 1,572,864 halves
  __f16* xpw_h  = (__f16*)(F + 14155776);  //   393,216 halves -> ends 14,352,384
  __f16* dwh    = (__f16*)(F + 14352384);  //   196,608 halves -> ends 14,450,688
  float* hend   = F + 14450688;            //   262,144
  float* Pp     = F + 14712832;            //   262,144 -> ends 14,974,976

  const int M = B_ * L_;                   // 2048
  dim3 blk(256);

  // one-time f16 packs
  packh<<<dim3(4096), blk, 0, stream>>>(x,   x_h,   1048576);
  packh<<<dim3(4096), blk, 0, stream>>>(wih, wih_h, 1048576);
  packh<<<dim3(6144), blk, 0, stream>>>(wo,  wo_h,  1572864);
  pack_xpw_h<<<dim3(1536), blk, 0, stream>>>(xpw, xpw_h);
  pack_dwh<<<dim3(768), blk, 0, stream>>>(dw, dwh);

  // LSTM input projection + recurrence
  gemm_mfma_h<0,false,false><<<dim3(16, 16), blk, 0, stream>>>(
      x_h, wih_h, gx, M, 2048, 512, 512, 512, 2048, bih, bhh);
  pack_whh<<<dim3(256), blk, 0, stream>>>(whh, wpk);
  lstm_rec<<<dim3(8), dim3(512), 0, stream>>>(gx, wpk, comb_h);

  for (int i = 0; i < NL; ++i) {
    const float* min = (i == 0) ? x : mbuf;
    const __f16* min_h = (i == 0) ? x_h : mbuf_h;
    packh<<<dim3(4096), blk, 0, stream>>>(wi + (size_t)i*1048576, wi_hc, 1048576);
    // xz = m @ in_proj^T
    gemm_mfma_h<0,false,false><<<dim3(16, 16), blk, 0, stream>>>(
        min_h, wi_hc, xz, M, 2048, 512, 512, 512, 2048, nullptr, nullptr);
    // u = silu(conv(xin)+cb)  (f32 + f16)
    conv_silu<<<dim3(8192), blk, 0, stream>>>(
        xz, cw + (size_t)i*DIN*DCV, cb + i*DIN, u, u_h);
    // xdbl = u @ xpw_pad^T  (f16 out, ld 128)
    gemm_mfma_h<0,false,true><<<dim3(1, 16), blk, 0, stream>>>(
        u_h, xpw_h + (size_t)i*131072, xdh, M, 128, 1024, 1024, 1024, 128, nullptr, nullptr);
    // dt = softplus(dt_in @ dt_proj^T + db)  (MFMA, K padded 32->64 w/ zero weights)
    gemm_mfma_h<1,false,false><<<dim3(8, 16), blk, 0, stream>>>(
        xdh, dwh + (size_t)i*65536, dt, M, 1024, 64, 128, 64, 1024, db + i*1024, nullptr);
    // chunked scan: pass A (chunk summaries) + pass B (fix & emit y)
    scan_part<<<dim3(1024), blk, 0, stream>>>(
        dt, u, xdh, Alog + (size_t)i*DIN*DST, hend, Pp);
    scan_fix<<<dim3(1024), blk, 0, stream>>>(
        dt, u, xdh, xz, Alog + (size_t)i*DIN*DST, Dp + i*DIN, hend, Pp, ybuf_h);
    // mo = y @ out_proj^T
    gemm_mfma_h<0,false,false><<<dim3(4, 16), blk, 0, stream>>>(
        ybuf_h, wo_h + (size_t)i*524288, mo, M, 512, 1024, 1024, 1024, 512, nullptr, nullptr);
    // m = LN(m + mo): layers 0,1 -> mbuf(+h); layer 2 -> comb cols [0,512)
    if (i < NL - 1)
      resid_ln<<<dim3(M), dim3(64), 0, stream>>>(
          min, mo, lng + i*512, lnb + i*512, mbuf, 512, mbuf_h, 512);
    else
      resid_ln<<<dim3(M), dim3(64), 0, stream>>>(
          min, mo, lng + i*512, lnb + i*512, nullptr, 0, comb_h, 1024);
  }

  // fusion: out = comb @ fusion_w^T + fb
  packh<<<dim3(2048), blk, 0, stream>>>(fw, fw_h, 524288);
  gemm_mfma_h<0,false,false><<<dim3(4, 16), blk, 0, stream>>>(
      comb_h, fw_h, out, M, 512, 1024, 1024, 1024, 512, fb, nullptr);
}

// Round 17
// 1347.421 us; speedup vs baseline: 4.4486x; 1.0586x over previous
//
#include <hip/hip_runtime.h>
#include <math.h>

#define B_  4
#define L_  512
#define D_  512
#define DIN 1024
#define DST 16
#define DCV 4
#define DTR 32
#define NL  3
#define H2  256
#define LCH 128   // scan chunk length
#define WSC 0.28f // lstm i8 weight scale

typedef _Float16 __f16;
typedef __f16 f16x2 __attribute__((ext_vector_type(2)));
typedef __f16 half8 __attribute__((ext_vector_type(8)));
typedef float f32x4v __attribute__((ext_vector_type(4)));
typedef unsigned uint4v __attribute__((ext_vector_type(4)));

__device__ __forceinline__ float fast_sigmoid(float x) { return 1.f / (1.f + __expf(-x)); }
__device__ __forceinline__ float fast_tanh(float x) { return 2.f / (1.f + __expf(-2.f * x)) - 1.f; }

__device__ __forceinline__ float dot2f(unsigned a, unsigned b, float c) {
  return __builtin_amdgcn_fdot2(__builtin_bit_cast(f16x2, a),
                                __builtin_bit_cast(f16x2, b), c, false);
}
__device__ __forceinline__ unsigned packf16(float a, float b) {
  f16x2 p; p.x = (__f16)a; p.y = (__f16)b;
  return __builtin_bit_cast(unsigned, p);
}
__device__ __forceinline__ int sdot4(unsigned a, unsigned b, int c) {
  return __builtin_amdgcn_sdot4((int)a, (int)b, c, false);
}
__device__ __forceinline__ int q8(float v) {
  float c = fmaxf(fminf(v, 127.f), -127.f);
  return (int)rintf(c);
}

// ---------------- f16-operand MFMA GEMM ----------------
template<int ACT, bool ACC, bool HOUT>
__global__ __launch_bounds__(256) void gemm_mfma_h(
    const __f16* __restrict__ A, const __f16* __restrict__ W, void* __restrict__ Cv,
    int M, int N, int K, int lda, int ldb, int ldc,
    const float* __restrict__ bias, const float* __restrict__ bias2)
{
  __shared__ uint4v As[1024];   // [row][8 kb-slots], phys slot = kb ^ (row&7)
  __shared__ uint4v Bs[1024];
  const int tid  = threadIdx.x;
  const int lane = tid & 63, wid = tid >> 6;
  const int wr = wid >> 1, wc = wid & 1;
  const int fr = lane & 15, fq = lane >> 4;
  const int m0 = blockIdx.y * 128, n0 = blockIdx.x * 128;
  const int srow = tid >> 3, skb = tid & 7;

  f32x4v acc[4][4] = {};
  for (int k0 = 0; k0 < K; k0 += 64) {
    const __f16* Ab = A + (size_t)m0 * lda + k0;
    const __f16* Bb = W + (size_t)n0 * ldb + k0;
    #pragma unroll
    for (int i = 0; i < 4; ++i) {
      int row = srow + i * 32;
      uint4v ap = *(const uint4v*)(Ab + (size_t)row * lda + skb * 8);
      uint4v bp = *(const uint4v*)(Bb + (size_t)row * ldb + skb * 8);
      As[row * 8 + (skb ^ (row & 7))] = ap;
      Bs[row * 8 + (skb ^ (row & 7))] = bp;
    }
    __syncthreads();
    #pragma unroll
    for (int ks = 0; ks < 2; ++ks) {
      half8 af[4], bf[4];
      #pragma unroll
      for (int mt = 0; mt < 4; ++mt) {
        int row = wr * 64 + mt * 16 + fr;
        int kb = ks * 4 + fq;
        af[mt] = __builtin_bit_cast(half8, As[row * 8 + (kb ^ (row & 7))]);
      }
      #pragma unroll
      for (int nt = 0; nt < 4; ++nt) {
        int row = wc * 64 + nt * 16 + fr;
        int kb = ks * 4 + fq;
        bf[nt] = __builtin_bit_cast(half8, Bs[row * 8 + (kb ^ (row & 7))]);
      }
      #pragma unroll
      for (int mt = 0; mt < 4; ++mt)
        #pragma unroll
        for (int nt = 0; nt < 4; ++nt)
          acc[mt][nt] = __builtin_amdgcn_mfma_f32_16x16x32_f16(af[mt], bf[nt], acc[mt][nt], 0, 0, 0);
    }
    __syncthreads();
  }
  float* C = (float*)Cv;
  __f16* Ch = (__f16*)Cv;
  #pragma unroll
  for (int nt = 0; nt < 4; ++nt) {
    int n = n0 + wc * 64 + nt * 16 + fr;
    float bv = (bias ? bias[n] : 0.f) + (bias2 ? bias2[n] : 0.f);
    #pragma unroll
    for (int mt = 0; mt < 4; ++mt) {
      #pragma unroll
      for (int r = 0; r < 4; ++r) {
        int m = m0 + wr * 64 + mt * 16 + fq * 4 + r;
        float v = acc[mt][nt][r] + bv;
        if (ACT == 1) v = (v > 20.f) ? v : log1pf(__expf(v));
        if (HOUT) Ch[(size_t)m * ldc + n] = (__f16)v;
        else if (ACC) C[(size_t)m * ldc + n] += v;
        else C[(size_t)m * ldc + n] = v;
      }
    }
  }
}

// generic f32 -> f16 pack
__global__ __launch_bounds__(256) void packh(
    const float* __restrict__ src, __f16* __restrict__ dst, int n)
{
  int t = blockIdx.x * 256 + threadIdx.x;
  if (t < n) dst[t] = (__f16)src[t];
}

// all 3 layers' x_proj weights, zero-padded 64->128 rows, packed f16
__global__ __launch_bounds__(256) void pack_xpw_h(
    const float* __restrict__ xpw, __f16* __restrict__ dst)
{
  int t = blockIdx.x * 256 + threadIdx.x;   // [0, 3*131072)
  int layer = t >> 17;
  int r = (t >> 10) & 127;
  int k = t & 1023;
  dst[t] = (r < 64) ? (__f16)xpw[layer * 65536 + r * 1024 + k] : (__f16)0.f;
}

// all 3 layers' dt_proj weights, zero-padded K 32->64, packed f16: [layer][1024][64]
__global__ __launch_bounds__(256) void pack_dwh(
    const float* __restrict__ dw, __f16* __restrict__ dst)
{
  int t = blockIdx.x * 256 + threadIdx.x;   // [0, 3*65536)
  int layer = t >> 16;
  int r = (t >> 6) & 1023;
  int k = t & 63;
  dst[t] = (k < 32) ? (__f16)dw[layer * 32768 + r * 32 + k] : (__f16)0.f;
}

// i,f,g gates -> i8 (fixed scale WSC), layout [dir][G][q][t] uint4, t=(j<<1)|ks
// uint4 idx covers whh[dir][G*256+j][ks*128 + q*16 .. +16)
__global__ __launch_bounds__(256) void pack_whh_i8(
    const float* __restrict__ whh, uint4* __restrict__ dst)
{
  int idx = blockIdx.x * 256 + threadIdx.x;   // [0, 24576)
  int t = idx & 511;
  int q = (idx >> 9) & 7;
  int r = idx >> 12;                          // [0, 6)
  int G = r % 3, dir = r / 3;
  int j = t >> 1, ks = t & 1;
  const float* src = whh + (size_t)dir * 262144 + (size_t)(G * 256 + j) * 256 + ks * 128 + q * 16;
  const float inv = 127.f / WSC;
  unsigned d[4];
  #pragma unroll
  for (int w = 0; w < 4; ++w) {
    float4 f = ((const float4*)src)[w];
    int q0 = q8(f.x * inv), q1 = q8(f.y * inv), q2 = q8(f.z * inv), q3 = q8(f.w * inv);
    d[w] = (unsigned)(q0 & 255) | ((unsigned)(q1 & 255) << 8) |
           ((unsigned)(q2 & 255) << 16) | ((unsigned)(q3 & 255) << 24);
  }
  uint4 pk; pk.x = d[0]; pk.y = d[1]; pk.z = d[2]; pk.w = d[3];
  dst[idx] = pk;
}

// o-gate f16, layout [dir][q in 16][t] uint4 (as before, G=3)
__global__ __launch_bounds__(256) void pack_whh_o(
    const float* __restrict__ whh, uint4* __restrict__ dst)
{
  int idx = blockIdx.x * 256 + threadIdx.x;   // [0, 16384)
  int t = idx & 511;
  int q = (idx >> 9) & 15;
  int dir = idx >> 13;
  int j = t >> 1, ks = t & 1;
  const float* src = whh + (size_t)dir * 262144 + (size_t)(768 + j) * 256 + ks * 128 + q * 8;
  float4 fa = ((const float4*)src)[0];
  float4 fb = ((const float4*)src)[1];
  uint4 pk;
  pk.x = packf16(fa.x, fa.y); pk.y = packf16(fa.z, fa.w);
  pk.z = packf16(fb.x, fb.y); pk.w = packf16(fb.z, fb.w);
  dst[idx] = pk;
}

// u[b,l,c] = silu(cb[c] + conv(xin)); dual write f32 + f16
__global__ __launch_bounds__(256) void conv_silu(
    const float* __restrict__ xz, const float* __restrict__ cw, const float* __restrict__ cb,
    float* __restrict__ u, __f16* __restrict__ uh)
{
  int t = blockIdx.x * 256 + threadIdx.x;
  int c  = t & (DIN - 1);
  int bl = t >> 10;
  int l  = bl & (L_ - 1);
  float acc = cb[c];
  #pragma unroll
  for (int k = 0; k < DCV; ++k) {
    int ls = l + k - (DCV - 1);
    if (ls >= 0)
      acc = fmaf(xz[(size_t)(bl + k - (DCV - 1)) * 2048 + c], cw[c * DCV + k], acc);
  }
  float v = acc * fast_sigmoid(acc);
  u[t] = v;
  uh[t] = (__f16)v;
}

// ---------------- chunked selective scan (2-pass, exact by linearity) ----------------
__global__ __launch_bounds__(256) void scan_part(
    const float* __restrict__ dt, const float* __restrict__ u,
    const __f16* __restrict__ xdh, const float* __restrict__ A_log,
    float* __restrict__ hend, float* __restrict__ Pp)
{
  int t = blockIdx.x * 256 + threadIdx.x;   // [0, 262144)
  int n  = t & 15;
  int ch = (t >> 4) & 3;
  int bc = t >> 6;
  int c  = bc & (DIN - 1);
  int b  = bc >> 10;
  float Ac = -__expf(A_log[c * DST + n]);
  float h = 0.f, P = 1.f;
  const size_t row = (size_t)b * L_ + ch * LCH;

#define DECLP(i) float dtv##i, uv##i, Bn##i;
  DECLP(0) DECLP(1) DECLP(2) DECLP(3)
#define LOADP(i, l) { \
    const size_t nb_ = row + (l); \
    dtv##i = dt[nb_ * DIN + c]; \
    uv##i  = u [nb_ * DIN + c]; \
    Bn##i  = (float)xdh[nb_ * 128 + 32 + n]; }
#define STEPP(i) { \
    float dA_ = __expf(dtv##i * Ac); \
    h = fmaf(dA_, h, (dtv##i * uv##i) * Bn##i); \
    P *= dA_; }

  LOADP(0, 0) LOADP(1, 1) LOADP(2, 2) LOADP(3, 3)
  for (int l = 0; l < LCH - 4; l += 4) {
    STEPP(0) LOADP(0, l + 4)
    STEPP(1) LOADP(1, l + 5)
    STEPP(2) LOADP(2, l + 6)
    STEPP(3) LOADP(3, l + 7)
  }
  STEPP(0) STEPP(1) STEPP(2) STEPP(3)
#undef DECLP
#undef LOADP
#undef STEPP
  int flat = bc * 16 + n;
  hend[ch * 65536 + flat] = h;
  Pp[ch * 65536 + flat]   = P;
}

__global__ __launch_bounds__(256) void scan_fix(
    const float* __restrict__ dt, const float* __restrict__ u,
    const __f16* __restrict__ xdh, const float* __restrict__ xz,
    const float* __restrict__ A_log, const float* __restrict__ Dp,
    const float* __restrict__ hend, const float* __restrict__ Pp,
    __f16* __restrict__ y)
{
  int t = blockIdx.x * 256 + threadIdx.x;   // [0, 262144)
  int n  = t & 15;
  int ch = (t >> 4) & 3;
  int bc = t >> 6;
  int c  = bc & (DIN - 1);
  int b  = bc >> 10;
  float Ac = -__expf(A_log[c * DST + n]);
  float Dc = Dp[c];
  const int flat = bc * 16 + n;
  float h = 0.f;
  if (ch > 0) h = hend[flat];
  if (ch > 1) h = fmaf(Pp[1 * 65536 + flat], h, hend[1 * 65536 + flat]);
  if (ch > 2) h = fmaf(Pp[2 * 65536 + flat], h, hend[2 * 65536 + flat]);
  const size_t row = (size_t)b * L_ + ch * LCH;

#define DECLP(i) float dtv##i, uv##i, Bn##i, Cn##i, zv##i;
  DECLP(0) DECLP(1) DECLP(2) DECLP(3)
#define LOADP(i, l) { \
    const size_t nb_ = row + (l); \
    dtv##i = dt[nb_ * DIN + c]; \
    uv##i  = u [nb_ * DIN + c]; \
    Bn##i  = (float)xdh[nb_ * 128 + 32 + n]; \
    Cn##i  = (float)xdh[nb_ * 128 + 48 + n]; \
    zv##i  = xz[nb_ * 2048 + 1024 + c]; }
#define STEPP(i, l) { \
    float dA_ = __expf(dtv##i * Ac); \
    h = fmaf(dA_, h, (dtv##i * uv##i) * Bn##i); \
    float p_ = h * Cn##i; \
    p_ += __shfl_xor(p_, 1, 64); \
    p_ += __shfl_xor(p_, 2, 64); \
    p_ += __shfl_xor(p_, 4, 64); \
    p_ += __shfl_xor(p_, 8, 64); \
    if (n == 0) { \
      float yv_ = p_ + uv##i * Dc; \
      yv_ *= zv##i * fast_sigmoid(zv##i); \
      y[(row + (l)) * DIN + c] = (__f16)yv_; \
    } }

  LOADP(0, 0) LOADP(1, 1) LOADP(2, 2) LOADP(3, 3)
  for (int l = 0; l < LCH - 4; l += 4) {
    STEPP(0, l)     LOADP(0, l + 4)
    STEPP(1, l + 1) LOADP(1, l + 5)
    STEPP(2, l + 2) LOADP(2, l + 6)
    STEPP(3, l + 3) LOADP(3, l + 7)
  }
  STEPP(0, LCH - 4) STEPP(1, LCH - 3) STEPP(2, LCH - 2) STEPP(3, LCH - 1)
#undef DECLP
#undef LOADP
#undef STEPP
}

// layernorm(a + mo)*g + b -> optional f32 out + f16 out
__global__ __launch_bounds__(64) void resid_ln(
    const float* __restrict__ a, const float* __restrict__ mo,
    const float* __restrict__ g, const float* __restrict__ bta,
    float* __restrict__ outm, int ldo, __f16* __restrict__ outh, int ldoh)
{
  int row = blockIdx.x;
  int lane = threadIdx.x;
  const float* pa = a  + (size_t)row * 512;
  const float* pb = mo + (size_t)row * 512;
  float v[8];
  float s = 0.f, s2 = 0.f;
  #pragma unroll
  for (int i = 0; i < 8; ++i) {
    float x = pa[lane + i * 64] + pb[lane + i * 64];
    v[i] = x; s += x; s2 += x * x;
  }
  #pragma unroll
  for (int off = 1; off < 64; off <<= 1) {
    s  += __shfl_xor(s,  off, 64);
    s2 += __shfl_xor(s2, off, 64);
  }
  float mean = s * (1.f / 512.f);
  float var  = s2 * (1.f / 512.f) - mean * mean;
  float rstd = rsqrtf(var + 1e-5f);
  #pragma unroll
  for (int i = 0; i < 8; ++i) {
    int cidx = lane + i * 64;
    float o = (v[i] - mean) * rstd * g[cidx] + bta[cidx];
    if (outm) outm[(size_t)row * ldo + cidx] = o;
    outh[(size_t)row * ldoh + cidx] = (__f16)o;
  }
}

// ---------------- LSTM recurrence: i8 i/f/g gates (sdot4) + f16 o-gate ----------------
// Block per (dir,b), 512 thr = (unit j=t>>1) x (K-half ks=t&1). Per step the
// i/f/g weights stream 192 KB from L2 (was 384 KB f16) and cost 96 sdot4
// (was 192 dot2); o-gate stays f16 from LDS (precision anchor). h published
// per-step as f16 pairs (h4s, for o) and i8 quads (h8s, for i/f/g).

#define W8DECL(q) uint4 WI8_##q, WF8_##q, WG8_##q;
#define W8LOAD(q) WI8_##q = wp8[(0*8+(q))*512 + t]; \
                  WF8_##q = wp8[(1*8+(q))*512 + t]; \
                  WG8_##q = wp8[(2*8+(q))*512 + t];
#define W8STEP(q) { \
    uint4 hq = h8s[buf][(q)*2 + ks]; \
    ii_ = sdot4(WI8_##q.x, hq.x, ii_); ii_ = sdot4(WI8_##q.y, hq.y, ii_); \
    ii_ = sdot4(WI8_##q.z, hq.z, ii_); ii_ = sdot4(WI8_##q.w, hq.w, ii_); \
    if_ = sdot4(WF8_##q.x, hq.x, if_); if_ = sdot4(WF8_##q.y, hq.y, if_); \
    if_ = sdot4(WF8_##q.z, hq.z, if_); if_ = sdot4(WF8_##q.w, hq.w, if_); \
    ig_ = sdot4(WG8_##q.x, hq.x, ig_); ig_ = sdot4(WG8_##q.y, hq.y, ig_); \
    ig_ = sdot4(WG8_##q.z, hq.z, ig_); ig_ = sdot4(WG8_##q.w, hq.w, ig_); }
#define OSTEP(q) { \
    uint4 hv = h4s[buf][(q)*2 + ks]; \
    uint4 wv = wo_lds[(q)*512 + t]; \
    a3 = dot2f(wv.x, hv.x, a3); a3 = dot2f(wv.y, hv.y, a3); \
    a3 = dot2f(wv.z, hv.z, a3); a3 = dot2f(wv.w, hv.w, a3); }
#define REP8(M) M(0) M(1) M(2) M(3) M(4) M(5) M(6) M(7)
#define REP16(M) M(0) M(1) M(2) M(3) M(4) M(5) M(6) M(7) \
                 M(8) M(9) M(10) M(11) M(12) M(13) M(14) M(15)

__global__ __launch_bounds__(512, 1) void lstm_rec(
    const float* __restrict__ gx, const uint4* __restrict__ wpk8,
    const uint4* __restrict__ wpko, __f16* __restrict__ comb)
{
  __shared__ uint4 wo_lds[16 * 512];            // [q][t], 128KB o-gate f16
  __shared__ __align__(16) uint4 h4s[2][32];    // f16 pairs, [buf][q*2+ks]
  __shared__ __align__(16) uint4 h8s[2][16];    // i8 quads, [buf][q*2+ks]
  const int dir = blockIdx.x >> 2, b = blockIdx.x & 3;
  const int t = threadIdx.x;
  const int j = t >> 1, ks = t & 1;
  const uint4* wp8 = wpk8 + (size_t)dir * 3 * 8 * 512;
  const uint4* wpo = wpko + (size_t)dir * 16 * 512;
  const float WS = WSC / (127.f * 127.f);

  REP8(W8DECL)
  REP8(W8LOAD)

  #pragma unroll
  for (int q = 0; q < 16; ++q)
    wo_lds[q * 512 + t] = wpo[q * 512 + t];

  if (t < 256) ((unsigned*)h4s)[t] = 0u;
  if (t < 128) ((unsigned*)h8s)[t] = 0u;
  float c_reg = 0.f;
  __f16* outp = comb + 512 + dir * 256;
  const float* gxb = gx + (size_t)(b * L_) * 2048 + dir * 1024;
  const int offA = (ks ? 1 : 0) * 256 + j;   // ks0 -> gate i, ks1 -> gate f
  const int offB = (ks ? 3 : 2) * 256 + j;   // ks0 -> gate g, ks1 -> gate o
  const int p_   = t >> 2;
  const int hidx = ((p_ >> 2) & 15) * 8 + (p_ >> 6) * 4 + (p_ & 3);
  // h8s writer (t%8==0): d = j>>2, entry/dword decode
  const int d_   = j >> 2;
  const int ks8  = d_ >> 5;
  const int h8i  = (((d_ - ks8 * 32) >> 2) * 2 + ks8) * 4 + (d_ & 3);
  __syncthreads();

  int buf = 0;
  const int l0 = dir ? (L_ - 1) : 0;
  float pgA = gxb[(size_t)l0 * 2048 + offA];
  float pgB = gxb[(size_t)l0 * 2048 + offB];

  for (int s = 0; s < L_; ++s) {
    const int l = dir ? (L_ - 1 - s) : s;
    float pgA_n = 0.f, pgB_n = 0.f;
    if (s + 1 < L_) {
      const int ln = dir ? (L_ - 2 - s) : (s + 1);
      pgA_n = gxb[(size_t)ln * 2048 + offA];
      pgB_n = gxb[(size_t)ln * 2048 + offB];
    }
    int ii_ = 0, if_ = 0, ig_ = 0;
    float a3 = 0.f;
    REP8(W8STEP)
    REP16(OSTEP)
    float a0 = (float)ii_ * WS;
    float a1 = (float)if_ * WS;
    float a2 = (float)ig_ * WS;
    if (ks == 0) { a0 += pgA; a2 += pgB; } else { a1 += pgA; a3 += pgB; }
    a0 += __shfl_xor(a0, 1, 64);
    a1 += __shfl_xor(a1, 1, 64);
    a2 += __shfl_xor(a2, 1, 64);
    a3 += __shfl_xor(a3, 1, 64);
    const float si = fast_sigmoid(a0);
    const float sf = fast_sigmoid(a1);
    const float tg = fast_tanh(a2);
    const float so = fast_sigmoid(a3);
    c_reg = fmaf(sf, c_reg, si * tg);
    const float hv = so * fast_tanh(c_reg);
    if (ks == 0) outp[(size_t)(b * L_ + l) * 1024 + j] = (__f16)hv;
    const float hv1 = __shfl_xor(hv, 2, 64);    // h[j+1] (for j even)
    const float hv2 = __shfl_xor(hv, 4, 64);    // h[j+2] (for j%4==0)
    const float hv3 = __shfl_xor(hv1, 4, 64);   // h[j+3] (for j%4==0)
    if ((t & 3) == 0)
      ((unsigned*)h4s[buf ^ 1])[hidx] = packf16(hv, hv1);
    if ((t & 7) == 0) {
      int q0 = (int)rintf(hv  * 127.f), q1 = (int)rintf(hv1 * 127.f);
      int q2 = (int)rintf(hv2 * 127.f), q3 = (int)rintf(hv3 * 127.f);
      ((unsigned*)h8s[buf ^ 1])[h8i] =
          (unsigned)(q0 & 255) | ((unsigned)(q1 & 255) << 8) |
          ((unsigned)(q2 & 255) << 16) | ((unsigned)(q3 & 255) << 24);
    }
    pgA = pgA_n; pgB = pgB_n;
    buf ^= 1;
    __syncthreads();
  }
}

extern "C" void kernel_launch(void* const* d_in, const int* in_sizes, int n_in,
                              void* d_out, int out_size, void* d_ws, size_t ws_size,
                              hipStream_t stream)
{
  const float* x    = (const float*)d_in[0];
  const float* wi   = (const float*)d_in[1];
  const float* cw   = (const float*)d_in[2];
  const float* cb   = (const float*)d_in[3];
  const float* xpw  = (const float*)d_in[4];
  const float* dw   = (const float*)d_in[5];
  const float* db   = (const float*)d_in[6];
  const float* Alog = (const float*)d_in[7];
  const float* Dp   = (const float*)d_in[8];
  const float* wo   = (const float*)d_in[9];
  const float* lng  = (const float*)d_in[10];
  const float* lnb  = (const float*)d_in[11];
  const float* wih  = (const float*)d_in[12];
  const float* whh  = (const float*)d_in[13];
  const float* bih  = (const float*)d_in[14];
  const float* bhh  = (const float*)d_in[15];
  const float* fw   = (const float*)d_in[16];
  const float* fb   = (const float*)d_in[17];
  float* out = (float*)d_out;

  float* F = (float*)d_ws;
  // f32 buffers
  float* xz     = F;                       // 4,194,304 (gx aliases; mo at +3,145,728)
  float* gx     = F;
  float* mo     = F + 3145728;             // 1,048,576
  float* u      = F + 4194304;             // 2,097,152
  __f16* xdh    = (__f16*)(F + 7340032);   // 262,144 halves (xdbl f16, ld 128)
  float* dt     = F + 7602176;             // 2,097,152 (ends 9,699,328)
  float* mbuf   = F + 10747904;            // 1,048,576
  // f16 / packed buffers (aliased into dead windows)
  __f16* fw_h   = (__f16*)(F + 4194304);   // in u region, packed after last u use
  __f16* u_h    = (__f16*)(F + 6291456);   // 2,097,152 halves
  __f16* wih_h  = (__f16*)(F + 7602176);   // in dt region (dead until first dt write)
  uint4* wpk8   = (uint4*)(F + 8126464);   // 24576 uint4 i8 i/f/g (ends 8,224,768)
  uint4* wpko   = (uint4*)(F + 8224768);   // 16384 uint4 f16 o   (ends 8,290,304)
  __f16* wi_hc  = (__f16*)(F + 8388608);   // in dt region, repacked per layer
  __f16* ybuf_h = (__f16*)(F + 9699328);   // 2,097,152 halves
  __f16* x_h    = (__f16*)(F + 9699328);   // aliases ybuf_h (dead before first scan)
  __f16* mbuf_h = (__f16*)(F + 11796480);  // 1,048,576 halves
  __f16* comb_h = (__f16*)(F + 12320768);  // 2,097,152 halves [m | lf | lb], ld 1024
  __f16* wo_h   = (__f16*)(F + 13369344);  // 1,572,864 halves
  __f16* xpw_h  = (__f16*)(F + 14155776);  //   393,216 halves -> ends 14,352,384
  __f16* dwh    = (__f16*)(F + 14352384);  //   196,608 halves -> ends 14,450,688
  float* hend   = F + 14450688;            //   262,144
  float* Pp     = F + 14712832;            //   262,144 -> ends 14,974,976

  const int M = B_ * L_;                   // 2048
  dim3 blk(256);

  // one-time packs
  packh<<<dim3(4096), blk, 0, stream>>>(x,   x_h,   1048576);
  packh<<<dim3(4096), blk, 0, stream>>>(wih, wih_h, 1048576);
  packh<<<dim3(6144), blk, 0, stream>>>(wo,  wo_h,  1572864);
  pack_xpw_h<<<dim3(1536), blk, 0, stream>>>(xpw, xpw_h);
  pack_dwh<<<dim3(768), blk, 0, stream>>>(dw, dwh);

  // LSTM input projection + recurrence
  gemm_mfma_h<0,false,false><<<dim3(16, 16), blk, 0, stream>>>(
      x_h, wih_h, gx, M, 2048, 512, 512, 512, 2048, bih, bhh);
  pack_whh_i8<<<dim3(96), blk, 0, stream>>>(whh, wpk8);
  pack_whh_o<<<dim3(64), blk, 0, stream>>>(whh, wpko);
  lstm_rec<<<dim3(8), dim3(512), 0, stream>>>(gx, wpk8, wpko, comb_h);

  for (int i = 0; i < NL; ++i) {
    const float* min = (i == 0) ? x : mbuf;
    const __f16* min_h = (i == 0) ? x_h : mbuf_h;
    packh<<<dim3(4096), blk, 0, stream>>>(wi + (size_t)i*1048576, wi_hc, 1048576);
    // xz = m @ in_proj^T
    gemm_mfma_h<0,false,false><<<dim3(16, 16), blk, 0, stream>>>(
        min_h, wi_hc, xz, M, 2048, 512, 512, 512, 2048, nullptr, nullptr);
    // u = silu(conv(xin)+cb)  (f32 + f16)
    conv_silu<<<dim3(8192), blk, 0, stream>>>(
        xz, cw + (size_t)i*DIN*DCV, cb + i*DIN, u, u_h);
    // xdbl = u @ xpw_pad^T  (f16 out, ld 128)
    gemm_mfma_h<0,false,true><<<dim3(1, 16), blk, 0, stream>>>(
        u_h, xpw_h + (size_t)i*131072, xdh, M, 128, 1024, 1024, 1024, 128, nullptr, nullptr);
    // dt = softplus(dt_in @ dt_proj^T + db)  (MFMA, K padded 32->64)
    gemm_mfma_h<1,false,false><<<dim3(8, 16), blk, 0, stream>>>(
        xdh, dwh + (size_t)i*65536, dt, M, 1024, 64, 128, 64, 1024, db + i*1024, nullptr);
    // chunked scan: pass A (summaries) + pass B (fix & emit y)
    scan_part<<<dim3(1024), blk, 0, stream>>>(
        dt, u, xdh, Alog + (size_t)i*DIN*DST, hend, Pp);
    scan_fix<<<dim3(1024), blk, 0, stream>>>(
        dt, u, xdh, xz, Alog + (size_t)i*DIN*DST, Dp + i*DIN, hend, Pp, ybuf_h);
    // mo = y @ out_proj^T
    gemm_mfma_h<0,false,false><<<dim3(4, 16), blk, 0, stream>>>(
        ybuf_h, wo_h + (size_t)i*524288, mo, M, 512, 1024, 1024, 1024, 512, nullptr, nullptr);
    // m = LN(m + mo): layers 0,1 -> mbuf(+h); layer 2 -> comb cols [0,512)
    if (i < NL - 1)
      resid_ln<<<dim3(M), dim3(64), 0, stream>>>(
          min, mo, lng + i*512, lnb + i*512, mbuf, 512, mbuf_h, 512);
    else
      resid_ln<<<dim3(M), dim3(64), 0, stream>>>(
          min, mo, lng + i*512, lnb + i*512, nullptr, 0, comb_h, 1024);
  }

  // fusion: out = comb @ fusion_w^T + fb
  packh<<<dim3(2048), blk, 0, stream>>>(fw, fw_h, 524288);
  gemm_mfma_h<0,false,false><<<dim3(4, 16), blk, 0, stream>>>(
      comb_h, fw_h, out, M, 512, 1024, 1024, 1024, 512, fb, nullptr);
}

// Round 18
// 1292.077 us; speedup vs baseline: 4.6392x; 1.0428x over previous
//
#include <hip/hip_runtime.h>
#include <math.h>

#define B_  4
#define L_  512
#define D_  512
#define DIN 1024
#define DST 16
#define DCV 4
#define DTR 32
#define NL  3
#define H2  256
#define LCH 64    // scan chunk length (8 chunks)
#define NCH 8
#define WSC 0.28f // lstm i8 weight scale

typedef _Float16 __f16;
typedef __f16 f16x2 __attribute__((ext_vector_type(2)));
typedef __f16 half8 __attribute__((ext_vector_type(8)));
typedef float f32x4v __attribute__((ext_vector_type(4)));
typedef unsigned uint4v __attribute__((ext_vector_type(4)));

__device__ __forceinline__ float fast_sigmoid(float x) { return 1.f / (1.f + __expf(-x)); }
__device__ __forceinline__ float fast_tanh(float x) { return 2.f / (1.f + __expf(-2.f * x)) - 1.f; }

__device__ __forceinline__ float dot2f(unsigned a, unsigned b, float c) {
  return __builtin_amdgcn_fdot2(__builtin_bit_cast(f16x2, a),
                                __builtin_bit_cast(f16x2, b), c, false);
}
__device__ __forceinline__ unsigned packf16(float a, float b) {
  f16x2 p; p.x = (__f16)a; p.y = (__f16)b;
  return __builtin_bit_cast(unsigned, p);
}
__device__ __forceinline__ int sdot4(unsigned a, unsigned b, int c) {
  return __builtin_amdgcn_sdot4((int)a, (int)b, c, false);
}
__device__ __forceinline__ int q8(float v) {
  float c = fmaxf(fminf(v, 127.f), -127.f);
  return (int)rintf(c);
}

// ---------------- f16-operand MFMA GEMM ----------------
template<int ACT, bool ACC, bool HOUT>
__global__ __launch_bounds__(256) void gemm_mfma_h(
    const __f16* __restrict__ A, const __f16* __restrict__ W, void* __restrict__ Cv,
    int M, int N, int K, int lda, int ldb, int ldc,
    const float* __restrict__ bias, const float* __restrict__ bias2)
{
  __shared__ uint4v As[1024];   // [row][8 kb-slots], phys slot = kb ^ (row&7)
  __shared__ uint4v Bs[1024];
  const int tid  = threadIdx.x;
  const int lane = tid & 63, wid = tid >> 6;
  const int wr = wid >> 1, wc = wid & 1;
  const int fr = lane & 15, fq = lane >> 4;
  const int m0 = blockIdx.y * 128, n0 = blockIdx.x * 128;
  const int srow = tid >> 3, skb = tid & 7;

  f32x4v acc[4][4] = {};
  for (int k0 = 0; k0 < K; k0 += 64) {
    const __f16* Ab = A + (size_t)m0 * lda + k0;
    const __f16* Bb = W + (size_t)n0 * ldb + k0;
    #pragma unroll
    for (int i = 0; i < 4; ++i) {
      int row = srow + i * 32;
      uint4v ap = *(const uint4v*)(Ab + (size_t)row * lda + skb * 8);
      uint4v bp = *(const uint4v*)(Bb + (size_t)row * ldb + skb * 8);
      As[row * 8 + (skb ^ (row & 7))] = ap;
      Bs[row * 8 + (skb ^ (row & 7))] = bp;
    }
    __syncthreads();
    #pragma unroll
    for (int ks = 0; ks < 2; ++ks) {
      half8 af[4], bf[4];
      #pragma unroll
      for (int mt = 0; mt < 4; ++mt) {
        int row = wr * 64 + mt * 16 + fr;
        int kb = ks * 4 + fq;
        af[mt] = __builtin_bit_cast(half8, As[row * 8 + (kb ^ (row & 7))]);
      }
      #pragma unroll
      for (int nt = 0; nt < 4; ++nt) {
        int row = wc * 64 + nt * 16 + fr;
        int kb = ks * 4 + fq;
        bf[nt] = __builtin_bit_cast(half8, Bs[row * 8 + (kb ^ (row & 7))]);
      }
      #pragma unroll
      for (int mt = 0; mt < 4; ++mt)
        #pragma unroll
        for (int nt = 0; nt < 4; ++nt)
          acc[mt][nt] = __builtin_amdgcn_mfma_f32_16x16x32_f16(af[mt], bf[nt], acc[mt][nt], 0, 0, 0);
    }
    __syncthreads();
  }
  float* C = (float*)Cv;
  __f16* Ch = (__f16*)Cv;
  #pragma unroll
  for (int nt = 0; nt < 4; ++nt) {
    int n = n0 + wc * 64 + nt * 16 + fr;
    float bv = (bias ? bias[n] : 0.f) + (bias2 ? bias2[n] : 0.f);
    #pragma unroll
    for (int mt = 0; mt < 4; ++mt) {
      #pragma unroll
      for (int r = 0; r < 4; ++r) {
        int m = m0 + wr * 64 + mt * 16 + fq * 4 + r;
        float v = acc[mt][nt][r] + bv;
        if (ACT == 1) v = (v > 20.f) ? v : log1pf(__expf(v));
        if (HOUT) Ch[(size_t)m * ldc + n] = (__f16)v;
        else if (ACC) C[(size_t)m * ldc + n] += v;
        else C[(size_t)m * ldc + n] = v;
      }
    }
  }
}

// generic f32 -> f16 pack
__global__ __launch_bounds__(256) void packh(
    const float* __restrict__ src, __f16* __restrict__ dst, int n)
{
  int t = blockIdx.x * 256 + threadIdx.x;
  if (t < n) dst[t] = (__f16)src[t];
}

// all 3 layers' x_proj weights, zero-padded 64->128 rows, packed f16
__global__ __launch_bounds__(256) void pack_xpw_h(
    const float* __restrict__ xpw, __f16* __restrict__ dst)
{
  int t = blockIdx.x * 256 + threadIdx.x;   // [0, 3*131072)
  int layer = t >> 17;
  int r = (t >> 10) & 127;
  int k = t & 1023;
  dst[t] = (r < 64) ? (__f16)xpw[layer * 65536 + r * 1024 + k] : (__f16)0.f;
}

// all 3 layers' dt_proj weights, zero-padded K 32->64, packed f16: [layer][1024][64]
__global__ __launch_bounds__(256) void pack_dwh(
    const float* __restrict__ dw, __f16* __restrict__ dst)
{
  int t = blockIdx.x * 256 + threadIdx.x;   // [0, 3*65536)
  int layer = t >> 16;
  int r = (t >> 6) & 1023;
  int k = t & 63;
  dst[t] = (k < 32) ? (__f16)dw[layer * 32768 + r * 32 + k] : (__f16)0.f;
}

// ALL 4 gates -> i8 (fixed scale WSC), layout [dir][G][q][t] uint4, t=(j<<1)|ks
// uint4 covers whh[dir][G*256+j][ks*128 + q*16 .. +16)
__global__ __launch_bounds__(256) void pack_whh_i8(
    const float* __restrict__ whh, uint4* __restrict__ dst)
{
  int idx = blockIdx.x * 256 + threadIdx.x;   // [0, 32768)
  int t = idx & 511;
  int q = (idx >> 9) & 7;
  int r = idx >> 12;                          // [0, 8)
  int G = r & 3, dir = r >> 2;
  int j = t >> 1, ks = t & 1;
  const float* src = whh + (size_t)dir * 262144 + (size_t)(G * 256 + j) * 256 + ks * 128 + q * 16;
  const float inv = 127.f / WSC;
  unsigned d[4];
  #pragma unroll
  for (int w = 0; w < 4; ++w) {
    float4 f = ((const float4*)src)[w];
    int q0 = q8(f.x * inv), q1 = q8(f.y * inv), q2 = q8(f.z * inv), q3 = q8(f.w * inv);
    d[w] = (unsigned)(q0 & 255) | ((unsigned)(q1 & 255) << 8) |
           ((unsigned)(q2 & 255) << 16) | ((unsigned)(q3 & 255) << 24);
  }
  uint4 pk; pk.x = d[0]; pk.y = d[1]; pk.z = d[2]; pk.w = d[3];
  dst[idx] = pk;
}

// u[b,l,c] = silu(cb[c] + conv(xin)); dual write f32 + f16
__global__ __launch_bounds__(256) void conv_silu(
    const float* __restrict__ xz, const float* __restrict__ cw, const float* __restrict__ cb,
    float* __restrict__ u, __f16* __restrict__ uh)
{
  int t = blockIdx.x * 256 + threadIdx.x;
  int c  = t & (DIN - 1);
  int bl = t >> 10;
  int l  = bl & (L_ - 1);
  float acc = cb[c];
  #pragma unroll
  for (int k = 0; k < DCV; ++k) {
    int ls = l + k - (DCV - 1);
    if (ls >= 0)
      acc = fmaf(xz[(size_t)(bl + k - (DCV - 1)) * 2048 + c], cw[c * DCV + k], acc);
  }
  float v = acc * fast_sigmoid(acc);
  u[t] = v;
  uh[t] = (__f16)v;
}

// ---------------- chunked selective scan (2-pass, exact by linearity) ----------------
// thread = (b, c, ch, n): n = t&15, ch = (t>>4)&7, bc = t>>7. 524288 threads.
__global__ __launch_bounds__(256) void scan_part(
    const float* __restrict__ dt, const float* __restrict__ u,
    const __f16* __restrict__ xdh, const float* __restrict__ A_log,
    float* __restrict__ hend, float* __restrict__ Pp)
{
  int t = blockIdx.x * 256 + threadIdx.x;   // [0, 524288)
  int n  = t & 15;
  int ch = (t >> 4) & 7;
  int bc = t >> 7;
  int c  = bc & (DIN - 1);
  int b  = bc >> 10;
  float Ac = -__expf(A_log[c * DST + n]);
  float h = 0.f, P = 1.f;
  const size_t row = (size_t)b * L_ + ch * LCH;

#define DECLP(i) float dtv##i, uv##i, Bn##i;
  DECLP(0) DECLP(1) DECLP(2) DECLP(3)
#define LOADP(i, l) { \
    const size_t nb_ = row + (l); \
    dtv##i = dt[nb_ * DIN + c]; \
    uv##i  = u [nb_ * DIN + c]; \
    Bn##i  = (float)xdh[nb_ * 128 + 32 + n]; }
#define STEPP(i) { \
    float dA_ = __expf(dtv##i * Ac); \
    h = fmaf(dA_, h, (dtv##i * uv##i) * Bn##i); \
    P *= dA_; }

  LOADP(0, 0) LOADP(1, 1) LOADP(2, 2) LOADP(3, 3)
  for (int l = 0; l < LCH - 4; l += 4) {
    STEPP(0) LOADP(0, l + 4)
    STEPP(1) LOADP(1, l + 5)
    STEPP(2) LOADP(2, l + 6)
    STEPP(3) LOADP(3, l + 7)
  }
  STEPP(0) STEPP(1) STEPP(2) STEPP(3)
#undef DECLP
#undef LOADP
#undef STEPP
  int flat = bc * 16 + n;
  hend[ch * 65536 + flat] = h;
  Pp[ch * 65536 + flat]   = P;
}

__global__ __launch_bounds__(256) void scan_fix(
    const float* __restrict__ dt, const float* __restrict__ u,
    const __f16* __restrict__ xdh, const float* __restrict__ xz,
    const float* __restrict__ A_log, const float* __restrict__ Dp,
    const float* __restrict__ hend, const float* __restrict__ Pp,
    __f16* __restrict__ y)
{
  int t = blockIdx.x * 256 + threadIdx.x;   // [0, 524288)
  int n  = t & 15;
  int ch = (t >> 4) & 7;
  int bc = t >> 7;
  int c  = bc & (DIN - 1);
  int b  = bc >> 10;
  float Ac = -__expf(A_log[c * DST + n]);
  float Dc = Dp[c];
  const int flat = bc * 16 + n;
  // fold predecessor chunk summaries: H = hend[c2] + P[c2]*H, c2 = 0..ch-1
  float h = 0.f;
  for (int c2 = 0; c2 < ch; ++c2)
    h = fmaf(Pp[c2 * 65536 + flat], h, hend[c2 * 65536 + flat]);
  const size_t row = (size_t)b * L_ + ch * LCH;

#define DECLP(i) float dtv##i, uv##i, Bn##i, Cn##i, zv##i;
  DECLP(0) DECLP(1) DECLP(2) DECLP(3)
#define LOADP(i, l) { \
    const size_t nb_ = row + (l); \
    dtv##i = dt[nb_ * DIN + c]; \
    uv##i  = u [nb_ * DIN + c]; \
    Bn##i  = (float)xdh[nb_ * 128 + 32 + n]; \
    Cn##i  = (float)xdh[nb_ * 128 + 48 + n]; \
    zv##i  = xz[nb_ * 2048 + 1024 + c]; }
#define STEPP(i, l) { \
    float dA_ = __expf(dtv##i * Ac); \
    h = fmaf(dA_, h, (dtv##i * uv##i) * Bn##i); \
    float p_ = h * Cn##i; \
    p_ += __shfl_xor(p_, 1, 64); \
    p_ += __shfl_xor(p_, 2, 64); \
    p_ += __shfl_xor(p_, 4, 64); \
    p_ += __shfl_xor(p_, 8, 64); \
    if (n == 0) { \
      float yv_ = p_ + uv##i * Dc; \
      yv_ *= zv##i * fast_sigmoid(zv##i); \
      y[(row + (l)) * DIN + c] = (__f16)yv_; \
    } }

  LOADP(0, 0) LOADP(1, 1) LOADP(2, 2) LOADP(3, 3)
  for (int l = 0; l < LCH - 4; l += 4) {
    STEPP(0, l)     LOADP(0, l + 4)
    STEPP(1, l + 1) LOADP(1, l + 5)
    STEPP(2, l + 2) LOADP(2, l + 6)
    STEPP(3, l + 3) LOADP(3, l + 7)
  }
  STEPP(0, LCH - 4) STEPP(1, LCH - 3) STEPP(2, LCH - 2) STEPP(3, LCH - 1)
#undef DECLP
#undef LOADP
#undef STEPP
}

// layernorm(a + mo)*g + b -> optional f32 out + f16 out
__global__ __launch_bounds__(64) void resid_ln(
    const float* __restrict__ a, const float* __restrict__ mo,
    const float* __restrict__ g, const float* __restrict__ bta,
    float* __restrict__ outm, int ldo, __f16* __restrict__ outh, int ldoh)
{
  int row = blockIdx.x;
  int lane = threadIdx.x;
  const float* pa = a  + (size_t)row * 512;
  const float* pb = mo + (size_t)row * 512;
  float v[8];
  float s = 0.f, s2 = 0.f;
  #pragma unroll
  for (int i = 0; i < 8; ++i) {
    float x = pa[lane + i * 64] + pb[lane + i * 64];
    v[i] = x; s += x; s2 += x * x;
  }
  #pragma unroll
  for (int off = 1; off < 64; off <<= 1) {
    s  += __shfl_xor(s,  off, 64);
    s2 += __shfl_xor(s2, off, 64);
  }
  float mean = s * (1.f / 512.f);
  float var  = s2 * (1.f / 512.f) - mean * mean;
  float rstd = rsqrtf(var + 1e-5f);
  #pragma unroll
  for (int i = 0; i < 8; ++i) {
    int cidx = lane + i * 64;
    float o = (v[i] - mean) * rstd * g[cidx] + bta[cidx];
    if (outm) outm[(size_t)row * ldo + cidx] = o;
    outh[(size_t)row * ldoh + cidx] = (__f16)o;
  }
}

// ---------------- LSTM recurrence: ALL gates i8 (sdot4) ----------------
// Block per (dir,b), 512 thr = (unit j=t>>1) x (K-half ks=t&1).
// i/f/g stream 192 KB/step from L2 (remat, unavoidable); o-gate i8 from LDS
// (64 KB/step, was 128 f16); h published ONLY as i8 quads (64 B/step).

#define W8DECL(q) uint4 WI8_##q, WF8_##q, WG8_##q;
#define W8LOAD(q) WI8_##q = wp8[(0*8+(q))*512 + t]; \
                  WF8_##q = wp8[(1*8+(q))*512 + t]; \
                  WG8_##q = wp8[(2*8+(q))*512 + t];
#define W8STEP(q) { \
    uint4 hq = h8s[buf][(q)*2 + ks]; \
    uint4 wo = wo_lds[(q)*512 + t]; \
    ii_ = sdot4(WI8_##q.x, hq.x, ii_); ii_ = sdot4(WI8_##q.y, hq.y, ii_); \
    ii_ = sdot4(WI8_##q.z, hq.z, ii_); ii_ = sdot4(WI8_##q.w, hq.w, ii_); \
    if_ = sdot4(WF8_##q.x, hq.x, if_); if_ = sdot4(WF8_##q.y, hq.y, if_); \
    if_ = sdot4(WF8_##q.z, hq.z, if_); if_ = sdot4(WF8_##q.w, hq.w, if_); \
    ig_ = sdot4(WG8_##q.x, hq.x, ig_); ig_ = sdot4(WG8_##q.y, hq.y, ig_); \
    ig_ = sdot4(WG8_##q.z, hq.z, ig_); ig_ = sdot4(WG8_##q.w, hq.w, ig_); \
    io_ = sdot4(wo.x, hq.x, io_); io_ = sdot4(wo.y, hq.y, io_); \
    io_ = sdot4(wo.z, hq.z, io_); io_ = sdot4(wo.w, hq.w, io_); }
#define REP8(M) M(0) M(1) M(2) M(3) M(4) M(5) M(6) M(7)

__global__ __launch_bounds__(512, 1) void lstm_rec(
    const float* __restrict__ gx, const uint4* __restrict__ wpk8,
    __f16* __restrict__ comb)
{
  __shared__ uint4 wo_lds[8 * 512];             // [q][t], 64KB o-gate i8
  __shared__ __align__(16) uint4 h8s[2][16];    // i8 h quads, [buf][q*2+ks]
  const int dir = blockIdx.x >> 2, b = blockIdx.x & 3;
  const int t = threadIdx.x;
  const int j = t >> 1, ks = t & 1;
  const uint4* wp8 = wpk8 + (size_t)dir * 4 * 8 * 512;
  const float WS = WSC / (127.f * 127.f);

  REP8(W8DECL)
  REP8(W8LOAD)

  #pragma unroll
  for (int q = 0; q < 8; ++q)
    wo_lds[q * 512 + t] = wp8[(3 * 8 + q) * 512 + t];

  if (t < 128) ((unsigned*)h8s)[t] = 0u;
  float c_reg = 0.f;
  __f16* outp = comb + 512 + dir * 256;
  const float* gxb = gx + (size_t)(b * L_) * 2048 + dir * 1024;
  const int offA = (ks ? 1 : 0) * 256 + j;   // ks0 -> gate i, ks1 -> gate f
  const int offB = (ks ? 3 : 2) * 256 + j;   // ks0 -> gate g, ks1 -> gate o
  // h8s writer (t%8==0): d = t>>3 covers h[4d..4d+3]
  const int d_   = t >> 3;
  const int ks8  = d_ >> 5;
  const int h8i  = (((d_ - ks8 * 32) >> 2) * 2 + ks8) * 4 + (d_ & 3);
  __syncthreads();

  int buf = 0;
  const int l0 = dir ? (L_ - 1) : 0;
  float pgA = gxb[(size_t)l0 * 2048 + offA];
  float pgB = gxb[(size_t)l0 * 2048 + offB];

  for (int s = 0; s < L_; ++s) {
    const int l = dir ? (L_ - 1 - s) : s;
    float pgA_n = 0.f, pgB_n = 0.f;
    if (s + 1 < L_) {
      const int ln = dir ? (L_ - 2 - s) : (s + 1);
      pgA_n = gxb[(size_t)ln * 2048 + offA];
      pgB_n = gxb[(size_t)ln * 2048 + offB];
    }
    int ii_ = 0, if_ = 0, ig_ = 0, io_ = 0;
    REP8(W8STEP)
    float a0 = (float)ii_ * WS;
    float a1 = (float)if_ * WS;
    float a2 = (float)ig_ * WS;
    float a3 = (float)io_ * WS;
    if (ks == 0) { a0 += pgA; a2 += pgB; } else { a1 += pgA; a3 += pgB; }
    a0 += __shfl_xor(a0, 1, 64);
    a1 += __shfl_xor(a1, 1, 64);
    a2 += __shfl_xor(a2, 1, 64);
    a3 += __shfl_xor(a3, 1, 64);
    const float si = fast_sigmoid(a0);
    const float sf = fast_sigmoid(a1);
    const float tg = fast_tanh(a2);
    const float so = fast_sigmoid(a3);
    c_reg = fmaf(sf, c_reg, si * tg);
    const float hv = so * fast_tanh(c_reg);
    if (ks == 0) outp[(size_t)(b * L_ + l) * 1024 + j] = (__f16)hv;
    const float hv1 = __shfl_xor(hv, 2, 64);    // h[j+1] (j even)
    const float hv2 = __shfl_xor(hv, 4, 64);    // h[j+2] (j%4==0)
    const float hv3 = __shfl_xor(hv1, 4, 64);   // h[j+3] (j%4==0)
    if ((t & 7) == 0) {
      int q0 = (int)rintf(hv  * 127.f), q1 = (int)rintf(hv1 * 127.f);
      int q2 = (int)rintf(hv2 * 127.f), q3 = (int)rintf(hv3 * 127.f);
      ((unsigned*)h8s[buf ^ 1])[h8i] =
          (unsigned)(q0 & 255) | ((unsigned)(q1 & 255) << 8) |
          ((unsigned)(q2 & 255) << 16) | ((unsigned)(q3 & 255) << 24);
    }
    pgA = pgA_n; pgB = pgB_n;
    buf ^= 1;
    __syncthreads();
  }
}

extern "C" void kernel_launch(void* const* d_in, const int* in_sizes, int n_in,
                              void* d_out, int out_size, void* d_ws, size_t ws_size,
                              hipStream_t stream)
{
  const float* x    = (const float*)d_in[0];
  const float* wi   = (const float*)d_in[1];
  const float* cw   = (const float*)d_in[2];
  const float* cb   = (const float*)d_in[3];
  const float* xpw  = (const float*)d_in[4];
  const float* dw   = (const float*)d_in[5];
  const float* db   = (const float*)d_in[6];
  const float* Alog = (const float*)d_in[7];
  const float* Dp   = (const float*)d_in[8];
  const float* wo   = (const float*)d_in[9];
  const float* lng  = (const float*)d_in[10];
  const float* lnb  = (const float*)d_in[11];
  const float* wih  = (const float*)d_in[12];
  const float* whh  = (const float*)d_in[13];
  const float* bih  = (const float*)d_in[14];
  const float* bhh  = (const float*)d_in[15];
  const float* fw   = (const float*)d_in[16];
  const float* fb   = (const float*)d_in[17];
  float* out = (float*)d_out;

  float* F = (float*)d_ws;
  // f32 buffers
  float* xz     = F;                       // 4,194,304 (gx aliases; mo at +3,145,728)
  float* gx     = F;
  float* mo     = F + 3145728;             // 1,048,576
  float* u      = F + 4194304;             // 2,097,152
  __f16* xdh    = (__f16*)(F + 7340032);   // 262,144 halves (xdbl f16, ld 128)
  float* dt     = F + 7602176;             // 2,097,152 (ends 9,699,328)
  float* mbuf   = F + 10747904;            // 1,048,576
  // f16 / packed buffers (aliased into dead windows)
  __f16* fw_h   = (__f16*)(F + 4194304);   // in u region, packed after last u use
  __f16* u_h    = (__f16*)(F + 6291456);   // 2,097,152 halves
  __f16* wih_h  = (__f16*)(F + 7602176);   // in dt region (dead until first dt write)
  uint4* wpk8   = (uint4*)(F + 8126464);   // 32768 uint4 i8, all 4 gates (ends 8,257,536)
  __f16* wi_hc  = (__f16*)(F + 8388608);   // in dt region, repacked per layer (1M halves)
  float* hend   = F + 8388608;             // aliases wi_hc region during scan (524,288)
  __f16* ybuf_h = (__f16*)(F + 9699328);   // 2,097,152 halves
  __f16* x_h    = (__f16*)(F + 9699328);   // aliases ybuf_h (dead before first scan)
  __f16* mbuf_h = (__f16*)(F + 11796480);  // 1,048,576 halves
  float* Pp     = F + 11796480;            // aliases mbuf_h region during scan (524,288)
  __f16* comb_h = (__f16*)(F + 12320768);  // 2,097,152 halves [m | lf | lb], ld 1024
  __f16* wo_h   = (__f16*)(F + 13369344);  // 1,572,864 halves
  __f16* xpw_h  = (__f16*)(F + 14155776);  //   393,216 halves -> ends 14,352,384
  __f16* dwh    = (__f16*)(F + 14352384);  //   196,608 halves -> ends 14,450,688

  const int M = B_ * L_;                   // 2048
  dim3 blk(256);

  // one-time packs
  packh<<<dim3(4096), blk, 0, stream>>>(x,   x_h,   1048576);
  packh<<<dim3(4096), blk, 0, stream>>>(wih, wih_h, 1048576);
  packh<<<dim3(6144), blk, 0, stream>>>(wo,  wo_h,  1572864);
  pack_xpw_h<<<dim3(1536), blk, 0, stream>>>(xpw, xpw_h);
  pack_dwh<<<dim3(768), blk, 0, stream>>>(dw, dwh);

  // LSTM input projection + recurrence
  gemm_mfma_h<0,false,false><<<dim3(16, 16), blk, 0, stream>>>(
      x_h, wih_h, gx, M, 2048, 512, 512, 512, 2048, bih, bhh);
  pack_whh_i8<<<dim3(128), blk, 0, stream>>>(whh, wpk8);
  lstm_rec<<<dim3(8), dim3(512), 0, stream>>>(gx, wpk8, comb_h);

  for (int i = 0; i < NL; ++i) {
    const float* min = (i == 0) ? x : mbuf;
    const __f16* min_h = (i == 0) ? x_h : mbuf_h;
    packh<<<dim3(4096), blk, 0, stream>>>(wi + (size_t)i*1048576, wi_hc, 1048576);
    // xz = m @ in_proj^T
    gemm_mfma_h<0,false,false><<<dim3(16, 16), blk, 0, stream>>>(
        min_h, wi_hc, xz, M, 2048, 512, 512, 512, 2048, nullptr, nullptr);
    // u = silu(conv(xin)+cb)  (f32 + f16)
    conv_silu<<<dim3(8192), blk, 0, stream>>>(
        xz, cw + (size_t)i*DIN*DCV, cb + i*DIN, u, u_h);
    // xdbl = u @ xpw_pad^T  (f16 out, ld 128)
    gemm_mfma_h<0,false,true><<<dim3(1, 16), blk, 0, stream>>>(
        u_h, xpw_h + (size_t)i*131072, xdh, M, 128, 1024, 1024, 1024, 128, nullptr, nullptr);
    // dt = softplus(dt_in @ dt_proj^T + db)  (MFMA, K padded 32->64)
    gemm_mfma_h<1,false,false><<<dim3(8, 16), blk, 0, stream>>>(
        xdh, dwh + (size_t)i*65536, dt, M, 1024, 64, 128, 64, 1024, db + i*1024, nullptr);
    // chunked scan: pass A (8 chunk summaries) + pass B (fold & emit y)
    scan_part<<<dim3(2048), blk, 0, stream>>>(
        dt, u, xdh, Alog + (size_t)i*DIN*DST, hend, Pp);
    scan_fix<<<dim3(2048), blk, 0, stream>>>(
        dt, u, xdh, xz, Alog + (size_t)i*DIN*DST, Dp + i*DIN, hend, Pp, ybuf_h);
    // mo = y @ out_proj^T
    gemm_mfma_h<0,false,false><<<dim3(4, 16), blk, 0, stream>>>(
        ybuf_h, wo_h + (size_t)i*524288, mo, M, 512, 1024, 1024, 1024, 512, nullptr, nullptr);
    // m = LN(m + mo): layers 0,1 -> mbuf(+h); layer 2 -> comb cols [0,512)
    if (i < NL - 1)
      resid_ln<<<dim3(M), dim3(64), 0, stream>>>(
          min, mo, lng + i*512, lnb + i*512, mbuf, 512, mbuf_h, 512);
    else
      resid_ln<<<dim3(M), dim3(64), 0, stream>>>(
          min, mo, lng + i*512, lnb + i*512, nullptr, 0, comb_h, 1024);
  }

  // fusion: out = comb @ fusion_w^T + fb
  packh<<<dim3(2048), blk, 0, stream>>>(fw, fw_h, 524288);
  gemm_mfma_h<0,false,false><<<dim3(4, 16), blk, 0, stream>>>(
      comb_h, fw_h, out, M, 512, 1024, 1024, 1024, 512, fb, nullptr);
}

// Round 19
// 1273.847 us; speedup vs baseline: 4.7056x; 1.0143x over previous
//
#include <hip/hip_runtime.h>
#include <math.h>

#define B_  4
#define L_  512
#define D_  512
#define DIN 1024
#define DST 16
#define DCV 4
#define DTR 32
#define NL  3
#define H2  256
#define LCH 64    // scan chunk length (8 chunks)
#define NCH 8
#define WSC 0.28f // lstm i8 weight scale

typedef _Float16 __f16;
typedef __f16 f16x2 __attribute__((ext_vector_type(2)));
typedef __f16 half8 __attribute__((ext_vector_type(8)));
typedef float f32x4v __attribute__((ext_vector_type(4)));
typedef unsigned uint4v __attribute__((ext_vector_type(4)));

__device__ __forceinline__ float fast_sigmoid(float x) { return 1.f / (1.f + __expf(-x)); }
__device__ __forceinline__ float fast_tanh(float x) { return 2.f / (1.f + __expf(-2.f * x)) - 1.f; }

__device__ __forceinline__ float dot2f(unsigned a, unsigned b, float c) {
  return __builtin_amdgcn_fdot2(__builtin_bit_cast(f16x2, a),
                                __builtin_bit_cast(f16x2, b), c, false);
}
__device__ __forceinline__ unsigned packf16(float a, float b) {
  f16x2 p; p.x = (__f16)a; p.y = (__f16)b;
  return __builtin_bit_cast(unsigned, p);
}
__device__ __forceinline__ int sdot4(unsigned a, unsigned b, int c) {
  return __builtin_amdgcn_sdot4((int)a, (int)b, c, false);
}
__device__ __forceinline__ int q8(float v) {
  float c = fmaxf(fminf(v, 127.f), -127.f);
  return (int)rintf(c);
}

// ---------------- f16-operand MFMA GEMM ----------------
template<int ACT, bool ACC, bool HOUT>
__global__ __launch_bounds__(256) void gemm_mfma_h(
    const __f16* __restrict__ A, const __f16* __restrict__ W, void* __restrict__ Cv,
    int M, int N, int K, int lda, int ldb, int ldc,
    const float* __restrict__ bias, const float* __restrict__ bias2)
{
  __shared__ uint4v As[1024];   // [row][8 kb-slots], phys slot = kb ^ (row&7)
  __shared__ uint4v Bs[1024];
  const int tid  = threadIdx.x;
  const int lane = tid & 63, wid = tid >> 6;
  const int wr = wid >> 1, wc = wid & 1;
  const int fr = lane & 15, fq = lane >> 4;
  const int m0 = blockIdx.y * 128, n0 = blockIdx.x * 128;
  const int srow = tid >> 3, skb = tid & 7;

  f32x4v acc[4][4] = {};
  for (int k0 = 0; k0 < K; k0 += 64) {
    const __f16* Ab = A + (size_t)m0 * lda + k0;
    const __f16* Bb = W + (size_t)n0 * ldb + k0;
    #pragma unroll
    for (int i = 0; i < 4; ++i) {
      int row = srow + i * 32;
      uint4v ap = *(const uint4v*)(Ab + (size_t)row * lda + skb * 8);
      uint4v bp = *(const uint4v*)(Bb + (size_t)row * ldb + skb * 8);
      As[row * 8 + (skb ^ (row & 7))] = ap;
      Bs[row * 8 + (skb ^ (row & 7))] = bp;
    }
    __syncthreads();
    #pragma unroll
    for (int ks = 0; ks < 2; ++ks) {
      half8 af[4], bf[4];
      #pragma unroll
      for (int mt = 0; mt < 4; ++mt) {
        int row = wr * 64 + mt * 16 + fr;
        int kb = ks * 4 + fq;
        af[mt] = __builtin_bit_cast(half8, As[row * 8 + (kb ^ (row & 7))]);
      }
      #pragma unroll
      for (int nt = 0; nt < 4; ++nt) {
        int row = wc * 64 + nt * 16 + fr;
        int kb = ks * 4 + fq;
        bf[nt] = __builtin_bit_cast(half8, Bs[row * 8 + (kb ^ (row & 7))]);
      }
      #pragma unroll
      for (int mt = 0; mt < 4; ++mt)
        #pragma unroll
        for (int nt = 0; nt < 4; ++nt)
          acc[mt][nt] = __builtin_amdgcn_mfma_f32_16x16x32_f16(af[mt], bf[nt], acc[mt][nt], 0, 0, 0);
    }
    __syncthreads();
  }
  float* C = (float*)Cv;
  __f16* Ch = (__f16*)Cv;
  #pragma unroll
  for (int nt = 0; nt < 4; ++nt) {
    int n = n0 + wc * 64 + nt * 16 + fr;
    float bv = (bias ? bias[n] : 0.f) + (bias2 ? bias2[n] : 0.f);
    #pragma unroll
    for (int mt = 0; mt < 4; ++mt) {
      #pragma unroll
      for (int r = 0; r < 4; ++r) {
        int m = m0 + wr * 64 + mt * 16 + fq * 4 + r;
        float v = acc[mt][nt][r] + bv;
        if (ACT == 1) v = (v > 20.f) ? v : log1pf(__expf(v));
        if (HOUT) Ch[(size_t)m * ldc + n] = (__f16)v;
        else if (ACC) C[(size_t)m * ldc + n] += v;
        else C[(size_t)m * ldc + n] = v;
      }
    }
  }
}

// generic f32 -> f16 pack
__global__ __launch_bounds__(256) void packh(
    const float* __restrict__ src, __f16* __restrict__ dst, int n)
{
  int t = blockIdx.x * 256 + threadIdx.x;
  if (t < n) dst[t] = (__f16)src[t];
}

// all 3 layers' x_proj weights, zero-padded 64->128 rows, packed f16
__global__ __launch_bounds__(256) void pack_xpw_h(
    const float* __restrict__ xpw, __f16* __restrict__ dst)
{
  int t = blockIdx.x * 256 + threadIdx.x;   // [0, 3*131072)
  int layer = t >> 17;
  int r = (t >> 10) & 127;
  int k = t & 1023;
  dst[t] = (r < 64) ? (__f16)xpw[layer * 65536 + r * 1024 + k] : (__f16)0.f;
}

// all 3 layers' dt_proj weights, zero-padded K 32->64, packed f16: [layer][1024][64]
__global__ __launch_bounds__(256) void pack_dwh(
    const float* __restrict__ dw, __f16* __restrict__ dst)
{
  int t = blockIdx.x * 256 + threadIdx.x;   // [0, 3*65536)
  int layer = t >> 16;
  int r = (t >> 6) & 1023;
  int k = t & 63;
  dst[t] = (k < 32) ? (__f16)dw[layer * 32768 + r * 32 + k] : (__f16)0.f;
}

// ALL 4 gates -> i8 (fixed scale WSC), layout [dir][G][q][t] uint4, t=(j<<1)|ks
// uint4 covers whh[dir][G*256+j][ks*128 + q*16 .. +16)
__global__ __launch_bounds__(256) void pack_whh_i8(
    const float* __restrict__ whh, uint4* __restrict__ dst)
{
  int idx = blockIdx.x * 256 + threadIdx.x;   // [0, 32768)
  int t = idx & 511;
  int q = (idx >> 9) & 7;
  int r = idx >> 12;                          // [0, 8)
  int G = r & 3, dir = r >> 2;
  int j = t >> 1, ks = t & 1;
  const float* src = whh + (size_t)dir * 262144 + (size_t)(G * 256 + j) * 256 + ks * 128 + q * 16;
  const float inv = 127.f / WSC;
  unsigned d[4];
  #pragma unroll
  for (int w = 0; w < 4; ++w) {
    float4 f = ((const float4*)src)[w];
    int q0 = q8(f.x * inv), q1 = q8(f.y * inv), q2 = q8(f.z * inv), q3 = q8(f.w * inv);
    d[w] = (unsigned)(q0 & 255) | ((unsigned)(q1 & 255) << 8) |
           ((unsigned)(q2 & 255) << 16) | ((unsigned)(q3 & 255) << 24);
  }
  uint4 pk; pk.x = d[0]; pk.y = d[1]; pk.z = d[2]; pk.w = d[3];
  dst[idx] = pk;
}

// u[b,l,c] = silu(cb[c] + conv(xin)); dual write f32 + f16
__global__ __launch_bounds__(256) void conv_silu(
    const float* __restrict__ xz, const float* __restrict__ cw, const float* __restrict__ cb,
    float* __restrict__ u, __f16* __restrict__ uh)
{
  int t = blockIdx.x * 256 + threadIdx.x;
  int c  = t & (DIN - 1);
  int bl = t >> 10;
  int l  = bl & (L_ - 1);
  float acc = cb[c];
  #pragma unroll
  for (int k = 0; k < DCV; ++k) {
    int ls = l + k - (DCV - 1);
    if (ls >= 0)
      acc = fmaf(xz[(size_t)(bl + k - (DCV - 1)) * 2048 + c], cw[c * DCV + k], acc);
  }
  float v = acc * fast_sigmoid(acc);
  u[t] = v;
  uh[t] = (__f16)v;
}

// ---------------- chunked selective scan (2-pass, exact by linearity) ----------------
__global__ __launch_bounds__(256) void scan_part(
    const float* __restrict__ dt, const float* __restrict__ u,
    const __f16* __restrict__ xdh, const float* __restrict__ A_log,
    float* __restrict__ hend, float* __restrict__ Pp)
{
  int t = blockIdx.x * 256 + threadIdx.x;   // [0, 524288)
  int n  = t & 15;
  int ch = (t >> 4) & 7;
  int bc = t >> 7;
  int c  = bc & (DIN - 1);
  int b  = bc >> 10;
  float Ac = -__expf(A_log[c * DST + n]);
  float h = 0.f, P = 1.f;
  const size_t row = (size_t)b * L_ + ch * LCH;

#define DECLP(i) float dtv##i, uv##i, Bn##i;
  DECLP(0) DECLP(1) DECLP(2) DECLP(3)
#define LOADP(i, l) { \
    const size_t nb_ = row + (l); \
    dtv##i = dt[nb_ * DIN + c]; \
    uv##i  = u [nb_ * DIN + c]; \
    Bn##i  = (float)xdh[nb_ * 128 + 32 + n]; }
#define STEPP(i) { \
    float dA_ = __expf(dtv##i * Ac); \
    h = fmaf(dA_, h, (dtv##i * uv##i) * Bn##i); \
    P *= dA_; }

  LOADP(0, 0) LOADP(1, 1) LOADP(2, 2) LOADP(3, 3)
  for (int l = 0; l < LCH - 4; l += 4) {
    STEPP(0) LOADP(0, l + 4)
    STEPP(1) LOADP(1, l + 5)
    STEPP(2) LOADP(2, l + 6)
    STEPP(3) LOADP(3, l + 7)
  }
  STEPP(0) STEPP(1) STEPP(2) STEPP(3)
#undef DECLP
#undef LOADP
#undef STEPP
  int flat = bc * 16 + n;
  hend[ch * 65536 + flat] = h;
  Pp[ch * 65536 + flat]   = P;
}

__global__ __launch_bounds__(256) void scan_fix(
    const float* __restrict__ dt, const float* __restrict__ u,
    const __f16* __restrict__ xdh, const float* __restrict__ xz,
    const float* __restrict__ A_log, const float* __restrict__ Dp,
    const float* __restrict__ hend, const float* __restrict__ Pp,
    __f16* __restrict__ y)
{
  int t = blockIdx.x * 256 + threadIdx.x;   // [0, 524288)
  int n  = t & 15;
  int ch = (t >> 4) & 7;
  int bc = t >> 7;
  int c  = bc & (DIN - 1);
  int b  = bc >> 10;
  float Ac = -__expf(A_log[c * DST + n]);
  float Dc = Dp[c];
  const int flat = bc * 16 + n;
  float h = 0.f;
  for (int c2 = 0; c2 < ch; ++c2)
    h = fmaf(Pp[c2 * 65536 + flat], h, hend[c2 * 65536 + flat]);
  const size_t row = (size_t)b * L_ + ch * LCH;

#define DECLP(i) float dtv##i, uv##i, Bn##i, Cn##i, zv##i;
  DECLP(0) DECLP(1) DECLP(2) DECLP(3)
#define LOADP(i, l) { \
    const size_t nb_ = row + (l); \
    dtv##i = dt[nb_ * DIN + c]; \
    uv##i  = u [nb_ * DIN + c]; \
    Bn##i  = (float)xdh[nb_ * 128 + 32 + n]; \
    Cn##i  = (float)xdh[nb_ * 128 + 48 + n]; \
    zv##i  = xz[nb_ * 2048 + 1024 + c]; }
#define STEPP(i, l) { \
    float dA_ = __expf(dtv##i * Ac); \
    h = fmaf(dA_, h, (dtv##i * uv##i) * Bn##i); \
    float p_ = h * Cn##i; \
    p_ += __shfl_xor(p_, 1, 64); \
    p_ += __shfl_xor(p_, 2, 64); \
    p_ += __shfl_xor(p_, 4, 64); \
    p_ += __shfl_xor(p_, 8, 64); \
    if (n == 0) { \
      float yv_ = p_ + uv##i * Dc; \
      yv_ *= zv##i * fast_sigmoid(zv##i); \
      y[(row + (l)) * DIN + c] = (__f16)yv_; \
    } }

  LOADP(0, 0) LOADP(1, 1) LOADP(2, 2) LOADP(3, 3)
  for (int l = 0; l < LCH - 4; l += 4) {
    STEPP(0, l)     LOADP(0, l + 4)
    STEPP(1, l + 1) LOADP(1, l + 5)
    STEPP(2, l + 2) LOADP(2, l + 6)
    STEPP(3, l + 3) LOADP(3, l + 7)
  }
  STEPP(0, LCH - 4) STEPP(1, LCH - 3) STEPP(2, LCH - 2) STEPP(3, LCH - 1)
#undef DECLP
#undef LOADP
#undef STEPP
}

// layernorm(a + mo)*g + b -> optional f32 out + f16 out
__global__ __launch_bounds__(64) void resid_ln(
    const float* __restrict__ a, const float* __restrict__ mo,
    const float* __restrict__ g, const float* __restrict__ bta,
    float* __restrict__ outm, int ldo, __f16* __restrict__ outh, int ldoh)
{
  int row = blockIdx.x;
  int lane = threadIdx.x;
  const float* pa = a  + (size_t)row * 512;
  const float* pb = mo + (size_t)row * 512;
  float v[8];
  float s = 0.f, s2 = 0.f;
  #pragma unroll
  for (int i = 0; i < 8; ++i) {
    float x = pa[lane + i * 64] + pb[lane + i * 64];
    v[i] = x; s += x; s2 += x * x;
  }
  #pragma unroll
  for (int off = 1; off < 64; off <<= 1) {
    s  += __shfl_xor(s,  off, 64);
    s2 += __shfl_xor(s2, off, 64);
  }
  float mean = s * (1.f / 512.f);
  float var  = s2 * (1.f / 512.f) - mean * mean;
  float rstd = rsqrtf(var + 1e-5f);
  #pragma unroll
  for (int i = 0; i < 8; ++i) {
    int cidx = lane + i * 64;
    float o = (v[i] - mean) * rstd * g[cidx] + bta[cidx];
    if (outm) outm[(size_t)row * ldo + cidx] = o;
    outh[(size_t)row * ldoh + cidx] = (__f16)o;
  }
}

// ---------------- LSTM recurrence: ALL gates i8; g+o from LDS, i+f from L2 ----------------
// Block per (dir,b), 512 thr = (unit j=t>>1) x (K-half ks=t&1).
// L2 stream: 128 KB/step (i,f; remat unavoidable). LDS stream: 128 KB/step (g,o).
// The two ports overlap, cutting the prior 192 KB L2 critical path.

#define W8DECL(q) uint4 WI8_##q, WF8_##q;
#define W8LOAD(q) WI8_##q = wp8[(0*8+(q))*512 + t]; \
                  WF8_##q = wp8[(1*8+(q))*512 + t];
#define W8STEP(q) { \
    uint4 hq = h8s[buf][(q)*2 + ks]; \
    uint4 wg = wg_lds[(q)*512 + t]; \
    uint4 wo = wo_lds[(q)*512 + t]; \
    ii_ = sdot4(WI8_##q.x, hq.x, ii_); ii_ = sdot4(WI8_##q.y, hq.y, ii_); \
    ii_ = sdot4(WI8_##q.z, hq.z, ii_); ii_ = sdot4(WI8_##q.w, hq.w, ii_); \
    if_ = sdot4(WF8_##q.x, hq.x, if_); if_ = sdot4(WF8_##q.y, hq.y, if_); \
    if_ = sdot4(WF8_##q.z, hq.z, if_); if_ = sdot4(WF8_##q.w, hq.w, if_); \
    ig_ = sdot4(wg.x, hq.x, ig_); ig_ = sdot4(wg.y, hq.y, ig_); \
    ig_ = sdot4(wg.z, hq.z, ig_); ig_ = sdot4(wg.w, hq.w, ig_); \
    io_ = sdot4(wo.x, hq.x, io_); io_ = sdot4(wo.y, hq.y, io_); \
    io_ = sdot4(wo.z, hq.z, io_); io_ = sdot4(wo.w, hq.w, io_); }
#define REP8(M) M(0) M(1) M(2) M(3) M(4) M(5) M(6) M(7)

__global__ __launch_bounds__(512, 1) void lstm_rec(
    const float* __restrict__ gx, const uint4* __restrict__ wpk8,
    __f16* __restrict__ comb)
{
  __shared__ uint4 wg_lds[8 * 512];             // 64KB g-gate i8
  __shared__ uint4 wo_lds[8 * 512];             // 64KB o-gate i8
  __shared__ __align__(16) uint4 h8s[2][16];    // i8 h quads, [buf][q*2+ks]
  const int dir = blockIdx.x >> 2, b = blockIdx.x & 3;
  const int t = threadIdx.x;
  const int j = t >> 1, ks = t & 1;
  const uint4* wp8 = wpk8 + (size_t)dir * 4 * 8 * 512;
  const float WS = WSC / (127.f * 127.f);

  REP8(W8DECL)
  REP8(W8LOAD)

  #pragma unroll
  for (int q = 0; q < 8; ++q) {
    wg_lds[q * 512 + t] = wp8[(2 * 8 + q) * 512 + t];
    wo_lds[q * 512 + t] = wp8[(3 * 8 + q) * 512 + t];
  }

  if (t < 128) ((unsigned*)h8s)[t] = 0u;
  float c_reg = 0.f;
  __f16* outp = comb + 512 + dir * 256;
  const float* gxb = gx + (size_t)(b * L_) * 2048 + dir * 1024;
  const int offA = (ks ? 1 : 0) * 256 + j;   // ks0 -> gate i, ks1 -> gate f
  const int offB = (ks ? 3 : 2) * 256 + j;   // ks0 -> gate g, ks1 -> gate o
  const int d_   = t >> 3;
  const int ks8  = d_ >> 5;
  const int h8i  = (((d_ - ks8 * 32) >> 2) * 2 + ks8) * 4 + (d_ & 3);
  __syncthreads();

  int buf = 0;
  const int l0 = dir ? (L_ - 1) : 0;
  float pgA = gxb[(size_t)l0 * 2048 + offA];
  float pgB = gxb[(size_t)l0 * 2048 + offB];

  for (int s = 0; s < L_; ++s) {
    const int l = dir ? (L_ - 1 - s) : s;
    float pgA_n = 0.f, pgB_n = 0.f;
    if (s + 1 < L_) {
      const int ln = dir ? (L_ - 2 - s) : (s + 1);
      pgA_n = gxb[(size_t)ln * 2048 + offA];
      pgB_n = gxb[(size_t)ln * 2048 + offB];
    }
    int ii_ = 0, if_ = 0, ig_ = 0, io_ = 0;
    REP8(W8STEP)
    float a0 = (float)ii_ * WS;
    float a1 = (float)if_ * WS;
    float a2 = (float)ig_ * WS;
    float a3 = (float)io_ * WS;
    if (ks == 0) { a0 += pgA; a2 += pgB; } else { a1 += pgA; a3 += pgB; }
    a0 += __shfl_xor(a0, 1, 64);
    a1 += __shfl_xor(a1, 1, 64);
    a2 += __shfl_xor(a2, 1, 64);
    a3 += __shfl_xor(a3, 1, 64);
    const float si = fast_sigmoid(a0);
    const float sf = fast_sigmoid(a1);
    const float tg = fast_tanh(a2);
    const float so = fast_sigmoid(a3);
    c_reg = fmaf(sf, c_reg, si * tg);
    const float hv = so * fast_tanh(c_reg);
    if (ks == 0) outp[(size_t)(b * L_ + l) * 1024 + j] = (__f16)hv;
    const float hv1 = __shfl_xor(hv, 2, 64);    // h[j+1] (j even)
    const float hv2 = __shfl_xor(hv, 4, 64);    // h[j+2] (j%4==0)
    const float hv3 = __shfl_xor(hv1, 4, 64);   // h[j+3] (j%4==0)
    if ((t & 7) == 0) {
      int q0 = (int)rintf(hv  * 127.f), q1 = (int)rintf(hv1 * 127.f);
      int q2 = (int)rintf(hv2 * 127.f), q3 = (int)rintf(hv3 * 127.f);
      ((unsigned*)h8s[buf ^ 1])[h8i] =
          (unsigned)(q0 & 255) | ((unsigned)(q1 & 255) << 8) |
          ((unsigned)(q2 & 255) << 16) | ((unsigned)(q3 & 255) << 24);
    }
    pgA = pgA_n; pgB = pgB_n;
    buf ^= 1;
    __syncthreads();
  }
}

extern "C" void kernel_launch(void* const* d_in, const int* in_sizes, int n_in,
                              void* d_out, int out_size, void* d_ws, size_t ws_size,
                              hipStream_t stream)
{
  const float* x    = (const float*)d_in[0];
  const float* wi   = (const float*)d_in[1];
  const float* cw   = (const float*)d_in[2];
  const float* cb   = (const float*)d_in[3];
  const float* xpw  = (const float*)d_in[4];
  const float* dw   = (const float*)d_in[5];
  const float* db   = (const float*)d_in[6];
  const float* Alog = (const float*)d_in[7];
  const float* Dp   = (const float*)d_in[8];
  const float* wo   = (const float*)d_in[9];
  const float* lng  = (const float*)d_in[10];
  const float* lnb  = (const float*)d_in[11];
  const float* wih  = (const float*)d_in[12];
  const float* whh  = (const float*)d_in[13];
  const float* bih  = (const float*)d_in[14];
  const float* bhh  = (const float*)d_in[15];
  const float* fw   = (const float*)d_in[16];
  const float* fb   = (const float*)d_in[17];
  float* out = (float*)d_out;

  float* F = (float*)d_ws;
  // f32 buffers
  float* xz     = F;                       // 4,194,304 (gx aliases; mo at +3,145,728)
  float* gx     = F;
  float* mo     = F + 3145728;             // 1,048,576
  float* u      = F + 4194304;             // 2,097,152
  __f16* xdh    = (__f16*)(F + 7340032);   // 262,144 halves (xdbl f16, ld 128)
  float* dt     = F + 7602176;             // 2,097,152 (ends 9,699,328)
  float* mbuf   = F + 10747904;            // 1,048,576
  // f16 / packed buffers (aliased into dead windows)
  __f16* fw_h   = (__f16*)(F + 4194304);   // in u region, packed after last u use
  __f16* u_h    = (__f16*)(F + 6291456);   // 2,097,152 halves
  __f16* wih_h  = (__f16*)(F + 7602176);   // in dt region (dead until first dt write)
  uint4* wpk8   = (uint4*)(F + 8126464);   // 32768 uint4 i8, all 4 gates (ends 8,257,536)
  __f16* wi_hc  = (__f16*)(F + 8388608);   // in dt region, repacked per layer (1M halves)
  float* hend   = F + 8388608;             // aliases wi_hc region during scan (524,288)
  __f16* ybuf_h = (__f16*)(F + 9699328);   // 2,097,152 halves
  __f16* x_h    = (__f16*)(F + 9699328);   // aliases ybuf_h (dead before first scan)
  __f16* mbuf_h = (__f16*)(F + 11796480);  // 1,048,576 halves
  float* Pp     = F + 11796480;            // aliases mbuf_h region during scan (524,288)
  __f16* comb_h = (__f16*)(F + 12320768);  // 2,097,152 halves [m | lf | lb], ld 1024
  __f16* wo_h   = (__f16*)(F + 13369344);  // 1,572,864 halves
  __f16* xpw_h  = (__f16*)(F + 14155776);  //   393,216 halves -> ends 14,352,384
  __f16* dwh    = (__f16*)(F + 14352384);  //   196,608 halves -> ends 14,450,688

  const int M = B_ * L_;                   // 2048
  dim3 blk(256);

  // one-time packs
  packh<<<dim3(4096), blk, 0, stream>>>(x,   x_h,   1048576);
  packh<<<dim3(4096), blk, 0, stream>>>(wih, wih_h, 1048576);
  packh<<<dim3(6144), blk, 0, stream>>>(wo,  wo_h,  1572864);
  pack_xpw_h<<<dim3(1536), blk, 0, stream>>>(xpw, xpw_h);
  pack_dwh<<<dim3(768), blk, 0, stream>>>(dw, dwh);

  // LSTM input projection + recurrence
  gemm_mfma_h<0,false,false><<<dim3(16, 16), blk, 0, stream>>>(
      x_h, wih_h, gx, M, 2048, 512, 512, 512, 2048, bih, bhh);
  pack_whh_i8<<<dim3(128), blk, 0, stream>>>(whh, wpk8);
  lstm_rec<<<dim3(8), dim3(512), 0, stream>>>(gx, wpk8, comb_h);

  for (int i = 0; i < NL; ++i) {
    const float* min = (i == 0) ? x : mbuf;
    const __f16* min_h = (i == 0) ? x_h : mbuf_h;
    packh<<<dim3(4096), blk, 0, stream>>>(wi + (size_t)i*1048576, wi_hc, 1048576);
    // xz = m @ in_proj^T
    gemm_mfma_h<0,false,false><<<dim3(16, 16), blk, 0, stream>>>(
        min_h, wi_hc, xz, M, 2048, 512, 512, 512, 2048, nullptr, nullptr);
    // u = silu(conv(xin)+cb)  (f32 + f16)
    conv_silu<<<dim3(8192), blk, 0, stream>>>(
        xz, cw + (size_t)i*DIN*DCV, cb + i*DIN, u, u_h);
    // xdbl = u @ xpw_pad^T  (f16 out, ld 128)
    gemm_mfma_h<0,false,true><<<dim3(1, 16), blk, 0, stream>>>(
        u_h, xpw_h + (size_t)i*131072, xdh, M, 128, 1024, 1024, 1024, 128, nullptr, nullptr);
    // dt = softplus(dt_in @ dt_proj^T + db)  (MFMA, K padded 32->64)
    gemm_mfma_h<1,false,false><<<dim3(8, 16), blk, 0, stream>>>(
        xdh, dwh + (size_t)i*65536, dt, M, 1024, 64, 128, 64, 1024, db + i*1024, nullptr);
    // chunked scan: pass A (8 chunk summaries) + pass B (fold & emit y)
    scan_part<<<dim3(2048), blk, 0, stream>>>(
        dt, u, xdh, Alog + (size_t)i*DIN*DST, hend, Pp);
    scan_fix<<<dim3(2048), blk, 0, stream>>>(
        dt, u, xdh, xz, Alog + (size_t)i*DIN*DST, Dp + i*DIN, hend, Pp, ybuf_h);
    // mo = y @ out_proj^T
    gemm_mfma_h<0,false,false><<<dim3(4, 16), blk, 0, stream>>>(
        ybuf_h, wo_h + (size_t)i*524288, mo, M, 512, 1024, 1024, 1024, 512, nullptr, nullptr);
    // m = LN(m + mo): layers 0,1 -> mbuf(+h); layer 2 -> comb cols [0,512)
    if (i < NL - 1)
      resid_ln<<<dim3(M), dim3(64), 0, stream>>>(
          min, mo, lng + i*512, lnb + i*512, mbuf, 512, mbuf_h, 512);
    else
      resid_ln<<<dim3(M), dim3(64), 0, stream>>>(
          min, mo, lng + i*512, lnb + i*512, nullptr, 0, comb_h, 1024);
  }

  // fusion: out = comb @ fusion_w^T + fb
  packh<<<dim3(2048), blk, 0, stream>>>(fw, fw_h, 524288);
  gemm_mfma_h<0,false,false><<<dim3(4, 16), blk, 0, stream>>>(
      comb_h, fw_h, out, M, 512, 1024, 1024, 1024, 512, fb, nullptr);
}